// Round 7
// baseline (514.040 us; speedup 1.0000x reference)
//
#include <hip/hip_runtime.h>
#include <hip/hip_bf16.h>
#include <math.h>

#define B_   2
#define Q_   2048
#define M_   2048
#define H_   16
#define D_   64
#define HID_ 1024
#define KL_  4096
#define RT_  128     // q rows per attention block
#define WT_  64      // k cols per attention tile
#define LSCL 0.022542110013890053f   // log2(e)/64 — logits kept in log2 units

typedef short short8 __attribute__((ext_vector_type(8)));
typedef short short4v __attribute__((ext_vector_type(4)));
typedef float f32x4 __attribute__((ext_vector_type(4)));
typedef float f32x16 __attribute__((ext_vector_type(16)));
typedef unsigned int uint2v __attribute__((ext_vector_type(2)));

__device__ __forceinline__ void async_copy16(const void* g, void* l) {
  __builtin_amdgcn_global_load_lds((const __attribute__((address_space(1))) unsigned int*)g,
                                   (__attribute__((address_space(3))) unsigned int*)l,
                                   16, 0, 0);
}

// read input element i as float, md=1 -> fp32 buffer, md=0 -> bf16 buffer
__device__ __forceinline__ float ldin(const void* p, size_t i, int md) {
  return md ? ((const float*)p)[i] : __bfloat162float(((const __hip_bfloat16*)p)[i]);
}

__device__ __forceinline__ short bfbits(float v) {
  __hip_bfloat16 t = __float2bfloat16(v);
  return *(short*)&t;
}

// fast 2^x: lowers to v_exp_f32 (HW computes 2^x natively)
__device__ __forceinline__ float fexp2(float x) { return exp2f(x); }

// ---------------- dtype detector: writes 1 if inputs are fp32, else 0 ----------------
__global__ __launch_bounds__(256) void detect_kernel(const unsigned int* __restrict__ q,
                                                     int* __restrict__ flag) {
  __shared__ int cnt;
  if (threadIdx.x == 0) cnt = 0;
  __syncthreads();
  int ins = 0;
#pragma unroll
  for (int i = 0; i < 4; i++) {
    unsigned int u = q[threadIdx.x * 4 + i];
    int e0 = (int)((u >> 7) & 0xffu);
    int e1 = (int)((u >> 23) & 0xffu);
    if (e0 == 0xff || e0 < 102 || e0 > 140) ins++;
    if (e1 == 0xff || e1 < 102 || e1 > 140) ins++;
  }
  atomicAdd(&cnt, ins);
  __syncthreads();
  if (threadIdx.x == 0) *flag = (cnt > 512) ? 1 : 0;
}

// ---------------- fused: 5 weight transposes (z<5) + sinusoidal pos-emb (z>=5) ----------------
__global__ __launch_bounds__(256) void wtpe_kernel(
    const void* __restrict__ s0, const void* __restrict__ s1, const void* __restrict__ s2,
    const void* __restrict__ s3, const void* __restrict__ s4,
    __hip_bfloat16* __restrict__ d0, __hip_bfloat16* __restrict__ d1,
    __hip_bfloat16* __restrict__ d2, __hip_bfloat16* __restrict__ d3,
    __hip_bfloat16* __restrict__ d4, __hip_bfloat16* __restrict__ pe,
    const int* __restrict__ mode) {
  const int tid = threadIdx.x;
  if (blockIdx.z >= 5) {
    // pos-emb: positions K-1..0
    const int p = (blockIdx.z - 5) * 256 + blockIdx.y * 16 + blockIdx.x;
    const float pos = (float)(KL_ - 1 - p);
#pragma unroll
    for (int i = 0; i < 4; i++) {
      int c = tid * 4 + i;
      int f = (c < 512) ? c : c - 512;
      float invf = fexp2(-(float)f * (13.287712379549449f / 512.0f));
      float a = pos * invf;
      float v = (c < 512) ? __sinf(a) : __cosf(a);
      pe[(size_t)p * HID_ + c] = __float2bfloat16(v);
    }
    return;
  }
  const int md = *mode;
  const void* src; __hip_bfloat16* dst;
  switch (blockIdx.z) {
    case 0: src = s0; dst = d0; break;
    case 1: src = s1; dst = d1; break;
    case 2: src = s2; dst = d2; break;
    case 3: src = s3; dst = d3; break;
    default: src = s4; dst = d4; break;
  }
  const int r0 = blockIdx.x * 64, c0 = blockIdx.y * 64;
  __shared__ __hip_bfloat16 t[64][65];
  const int col = tid & 63, r4 = tid >> 6;
#pragma unroll
  for (int i = 0; i < 16; i++)
    t[r4 + i * 4][col] = __float2bfloat16(ldin(src, (size_t)(r0 + r4 + i * 4) * HID_ + c0 + col, md));
  __syncthreads();
#pragma unroll
  for (int i = 0; i < 16; i++)
    dst[(size_t)(c0 + r4 + i * 4) * HID_ + r0 + col] = t[col][r4 + i * 4];
}

// ---------------- fused LayerNorm: rows [0,B*KL) = concat(mem,query); rows >= B*KL = query ----------------
__global__ __launch_bounds__(256) void ln_kernel(
    const void* __restrict__ mem, const void* __restrict__ qry,
    const void* __restrict__ gmem, const void* __restrict__ bmem,
    const void* __restrict__ gq, const void* __restrict__ bq,
    __hip_bfloat16* __restrict__ kvout, __hip_bfloat16* __restrict__ qout,
    const int* __restrict__ mode) {
  const int md = *mode;
  const int row = blockIdx.x;  // 0..B*KL + B*Q - 1
  const void* src;
  const void* gamma; const void* beta;
  size_t base;
  __hip_bfloat16* dst;
  if (row < B_ * KL_) {
    const int b = row / KL_, j = row % KL_;
    if (j < M_) { src = mem; base = ((size_t)b * M_ + j) * HID_; }
    else        { src = qry; base = ((size_t)b * Q_ + (j - M_)) * HID_; }
    gamma = gmem; beta = bmem;
    dst = kvout + (size_t)row * HID_;
  } else {
    const int r = row - B_ * KL_;
    src = qry; base = (size_t)r * HID_;
    gamma = gq; beta = bq;
    dst = qout + (size_t)r * HID_;
  }
  const int tid = threadIdx.x;
  float x[4];
  float s = 0.f, ss = 0.f;
#pragma unroll
  for (int i = 0; i < 4; i++) {
    x[i] = ldin(src, base + i * 256 + tid, md);
    s += x[i]; ss += x[i] * x[i];
  }
#pragma unroll
  for (int o = 32; o > 0; o >>= 1) { s += __shfl_down(s, o); ss += __shfl_down(ss, o); }
  __shared__ float red[8];
  if ((tid & 63) == 0) { red[(tid >> 6) * 2] = s; red[(tid >> 6) * 2 + 1] = ss; }
  __syncthreads();
  float ts = 0.f, tss = 0.f;
#pragma unroll
  for (int i = 0; i < 4; i++) { ts += red[i * 2]; tss += red[i * 2 + 1]; }
  const float mu = ts * (1.f / 1024.f);
  const float var = tss * (1.f / 1024.f) - mu * mu;
  const float rs = rsqrtf(var + 1e-3f);
#pragma unroll
  for (int i = 0; i < 4; i++) {
    int c = i * 256 + tid;
    dst[c] = __float2bfloat16((x[i] - mu) * rs * ldin(gamma, c, md) + ldin(beta, c, md));
  }
}

// ---------------- GEMM core: C = A @ BT^T (both bf16, K=1024), 128x128 tile ----------------
template <int WRITE_MODE_SWITCH>
__device__ __forceinline__ void gemm_body(const __hip_bfloat16* __restrict__ A,
                                          const __hip_bfloat16* __restrict__ BT,
                                          void* __restrict__ C, int md, float scl) {
  __shared__ __attribute__((aligned(16))) __hip_bfloat16 sA[128 * 32];
  __shared__ __attribute__((aligned(16))) __hip_bfloat16 sB[128 * 32];
  const int tid = threadIdx.x;
  const int lane = tid & 63;
  const int w = tid >> 6;
  const int quad = lane >> 4, l16 = lane & 15;
  const int m0 = blockIdx.x * 128;
  const int n0 = blockIdx.y * 128;
  const int wm = (w >> 1) * 64, wn = (w & 1) * 64;
  const f32x4 fz = {0.f, 0.f, 0.f, 0.f};

  f32x4 acc[4][4];
#pragma unroll
  for (int i = 0; i < 4; i++)
#pragma unroll
    for (int j = 0; j < 4; j++) acc[i][j] = fz;

  for (int kk = 0; kk < HID_ / 32; kk++) {
    const int k0 = kk * 32;
    __syncthreads();
#pragma unroll
    for (int t = 0; t < 2; t++) {
      int c = (w * 2 + t) * 64 + lane;
      int row = c >> 2;
      int cid = (c & 3) ^ (row & 3);
      async_copy16(A + (size_t)(m0 + row) * HID_ + k0 + cid * 8, (char*)sA + c * 16);
      async_copy16(BT + (size_t)(n0 + row) * HID_ + k0 + cid * 8, (char*)sB + c * 16);
    }
    __syncthreads();
    short8 af[4], bf[4];
#pragma unroll
    for (int mt = 0; mt < 4; mt++) {
      int r = wm + mt * 16 + l16;
      af[mt] = *(const short8*)((const char*)sA + r * 64 + ((quad ^ (r & 3)) * 16));
    }
#pragma unroll
    for (int nt = 0; nt < 4; nt++) {
      int r = wn + nt * 16 + l16;
      bf[nt] = *(const short8*)((const char*)sB + r * 64 + ((quad ^ (r & 3)) * 16));
    }
#pragma unroll
    for (int mt = 0; mt < 4; mt++)
#pragma unroll
      for (int nt = 0; nt < 4; nt++)
        acc[mt][nt] = __builtin_amdgcn_mfma_f32_16x16x32_bf16(af[mt], bf[nt], acc[mt][nt], 0, 0, 0);
  }
#pragma unroll
  for (int mt = 0; mt < 4; mt++)
#pragma unroll
    for (int nt = 0; nt < 4; nt++)
#pragma unroll
      for (int rg = 0; rg < 4; rg++) {
        int r = m0 + wm + mt * 16 + quad * 4 + rg;
        int cc = n0 + wn + nt * 16 + l16;
        size_t idx = (size_t)r * HID_ + cc;
        if (WRITE_MODE_SWITCH && md) ((float*)C)[idx] = acc[mt][nt][rg];
        else ((__hip_bfloat16*)C)[idx] = __float2bfloat16(acc[mt][nt][rg] * scl);
      }
}

__global__ __launch_bounds__(256) void gemm_bt128(const __hip_bfloat16* __restrict__ A,
                                                  const __hip_bfloat16* __restrict__ BT,
                                                  __hip_bfloat16* __restrict__ C, float scl) {
  gemm_body<0>(A, BT, (void*)C, 0, scl);
}

__global__ __launch_bounds__(256) void gemm_out(const __hip_bfloat16* __restrict__ A,
                                                const __hip_bfloat16* __restrict__ BT,
                                                void* __restrict__ C,
                                                const int* __restrict__ mode) {
  gemm_body<1>(A, BT, C, *mode, 1.0f);
}

// ---- q-projection GEMM with dual-bias epilogue: qw=(acc+rwb)*LSCL, qr=(acc+rrb)*LSCL ----
__global__ __launch_bounds__(256) void gemm_q(const __hip_bfloat16* __restrict__ A,
                                              const __hip_bfloat16* __restrict__ BT,
                                              const void* __restrict__ rwb,
                                              const void* __restrict__ rrb,
                                              __hip_bfloat16* __restrict__ qw,
                                              __hip_bfloat16* __restrict__ qr,
                                              const int* __restrict__ mode) {
  const int md = *mode;
  __shared__ __attribute__((aligned(16))) __hip_bfloat16 sA[128 * 32];
  __shared__ __attribute__((aligned(16))) __hip_bfloat16 sB[128 * 32];
  const int tid = threadIdx.x;
  const int lane = tid & 63;
  const int w = tid >> 6;
  const int quad = lane >> 4, l16 = lane & 15;
  const int m0 = blockIdx.x * 128;
  const int n0 = blockIdx.y * 128;
  const int wm = (w >> 1) * 64, wn = (w & 1) * 64;
  const f32x4 fz = {0.f, 0.f, 0.f, 0.f};

  f32x4 acc[4][4];
#pragma unroll
  for (int i = 0; i < 4; i++)
#pragma unroll
    for (int j = 0; j < 4; j++) acc[i][j] = fz;

  for (int kk = 0; kk < HID_ / 32; kk++) {
    const int k0 = kk * 32;
    __syncthreads();
#pragma unroll
    for (int t = 0; t < 2; t++) {
      int c = (w * 2 + t) * 64 + lane;
      int row = c >> 2;
      int cid = (c & 3) ^ (row & 3);
      async_copy16(A + (size_t)(m0 + row) * HID_ + k0 + cid * 8, (char*)sA + c * 16);
      async_copy16(BT + (size_t)(n0 + row) * HID_ + k0 + cid * 8, (char*)sB + c * 16);
    }
    __syncthreads();
    short8 af[4], bf[4];
#pragma unroll
    for (int mt = 0; mt < 4; mt++) {
      int r = wm + mt * 16 + l16;
      af[mt] = *(const short8*)((const char*)sA + r * 64 + ((quad ^ (r & 3)) * 16));
    }
#pragma unroll
    for (int nt = 0; nt < 4; nt++) {
      int r = wn + nt * 16 + l16;
      bf[nt] = *(const short8*)((const char*)sB + r * 64 + ((quad ^ (r & 3)) * 16));
    }
#pragma unroll
    for (int mt = 0; mt < 4; mt++)
#pragma unroll
      for (int nt = 0; nt < 4; nt++)
        acc[mt][nt] = __builtin_amdgcn_mfma_f32_16x16x32_bf16(af[mt], bf[nt], acc[mt][nt], 0, 0, 0);
  }
  float bw[4], br[4];
#pragma unroll
  for (int nt = 0; nt < 4; nt++) {
    int cc = n0 + wn + nt * 16 + l16;
    bw[nt] = ldin(rwb, cc, md);
    br[nt] = ldin(rrb, cc, md);
  }
#pragma unroll
  for (int mt = 0; mt < 4; mt++)
#pragma unroll
    for (int nt = 0; nt < 4; nt++)
#pragma unroll
      for (int rg = 0; rg < 4; rg++) {
        int r = m0 + wm + mt * 16 + quad * 4 + rg;
        int cc = n0 + wn + nt * 16 + l16;
        size_t idx = (size_t)r * HID_ + cc;
        float a = acc[mt][nt][rg];
        qw[idx] = __float2bfloat16((a + bw[nt]) * LSCL);
        qr[idx] = __float2bfloat16((a + br[nt]) * LSCL);
      }
}

// ---- dual GEMM: BT = contiguous [wkT; wvT]; K-half -> kpb (row-major), V-half -> vpt
// (transposed per-head layout [b][h][d][j]) via in-block LDS transpose epilogue. ----
__global__ __launch_bounds__(256) void gemm_dualv(const __hip_bfloat16* __restrict__ A,
                                                  const __hip_bfloat16* __restrict__ BT,
                                                  __hip_bfloat16* __restrict__ C0,
                                                  __hip_bfloat16* __restrict__ vpt) {
  __shared__ __attribute__((aligned(16))) __hip_bfloat16 sA[128 * 32];
  __shared__ __attribute__((aligned(16))) __hip_bfloat16 sB[128 * 32];
  __shared__ __attribute__((aligned(16))) short sT[128 * 136];  // 34816 B, pad row 272B
  const int tid = threadIdx.x;
  const int lane = tid & 63;
  const int w = tid >> 6;
  const int quad = lane >> 4, l16 = lane & 15;
  const int m0 = blockIdx.x * 128;
  const int n0 = blockIdx.y * 128;  // 0..1920
  const int wm = (w >> 1) * 64, wn = (w & 1) * 64;
  const f32x4 fz = {0.f, 0.f, 0.f, 0.f};

  f32x4 acc[4][4];
#pragma unroll
  for (int i = 0; i < 4; i++)
#pragma unroll
    for (int j = 0; j < 4; j++) acc[i][j] = fz;

  for (int kk = 0; kk < HID_ / 32; kk++) {
    const int k0 = kk * 32;
    __syncthreads();
#pragma unroll
    for (int t = 0; t < 2; t++) {
      int c = (w * 2 + t) * 64 + lane;
      int row = c >> 2;
      int cid = (c & 3) ^ (row & 3);
      async_copy16(A + (size_t)(m0 + row) * HID_ + k0 + cid * 8, (char*)sA + c * 16);
      async_copy16(BT + (size_t)(n0 + row) * HID_ + k0 + cid * 8, (char*)sB + c * 16);
    }
    __syncthreads();
    short8 af[4], bf[4];
#pragma unroll
    for (int mt = 0; mt < 4; mt++) {
      int r = wm + mt * 16 + l16;
      af[mt] = *(const short8*)((const char*)sA + r * 64 + ((quad ^ (r & 3)) * 16));
    }
#pragma unroll
    for (int nt = 0; nt < 4; nt++) {
      int r = wn + nt * 16 + l16;
      bf[nt] = *(const short8*)((const char*)sB + r * 64 + ((quad ^ (r & 3)) * 16));
    }
#pragma unroll
    for (int mt = 0; mt < 4; mt++)
#pragma unroll
      for (int nt = 0; nt < 4; nt++)
        acc[mt][nt] = __builtin_amdgcn_mfma_f32_16x16x32_bf16(af[mt], bf[nt], acc[mt][nt], 0, 0, 0);
  }
  if (n0 < HID_) {
    // K half: row-major write
#pragma unroll
    for (int mt = 0; mt < 4; mt++)
#pragma unroll
      for (int nt = 0; nt < 4; nt++)
#pragma unroll
        for (int rg = 0; rg < 4; rg++) {
          int r = m0 + wm + mt * 16 + quad * 4 + rg;
          int cc = n0 + wn + nt * 16 + l16;
          C0[(size_t)r * HID_ + cc] = __float2bfloat16(acc[mt][nt][rg]);
        }
  } else {
    // V half: transpose through sT -> vpt[((b*H+h)*D+d)*KL + j]
#pragma unroll
    for (int mt = 0; mt < 4; mt++)
#pragma unroll
      for (int nt = 0; nt < 4; nt++) {
        int r = wm + mt * 16 + quad * 4;   // local j base (rg 0..3 consecutive)
        int cc = wn + nt * 16 + l16;       // local col
        short4v pk;
#pragma unroll
        for (int rg = 0; rg < 4; rg++) pk[rg] = bfbits(acc[mt][nt][rg]);
        *(short4v*)&sT[cc * 136 + r] = pk;
      }
    __syncthreads();
    const int b = m0 >> 12;            // 4096 rows per batch
    const int j0g = m0 & (KL_ - 1);
    const int cg0 = n0 - HID_;
#pragma unroll
    for (int it = 0; it < 16; it++) {
      int cc = it * 8 + w * 2 + (lane >> 5);
      int jj = (lane & 31) * 4;
      int cg = cg0 + cc;
      int h = cg >> 6, d = cg & 63;
      short4v v = *(const short4v*)&sT[cc * 136 + jj];
      *(short4v*)(vpt + (((size_t)(b * H_ + h)) * D_ + d) * KL_ + j0g + jj) = v;
    }
  }
}

// ---------------- fused relative attention, 32x32 MFMA, single-barrier pipeline ----------------
// grid 512 (all-resident: 2 blocks/CU, rank-flipped so each CU's pair is long+short),
// block 256 (4 waves x 32 q-rows). RT=128, WT=64, mfma_f32_32x32x16_bf16.
// K: double-buffered LDS (2x8K). rel: 256-row circular LDS band (32K) — commit rows are
// disjoint from the tile's reads, so no pre-read barrier. V^T: never in LDS — per-lane
// fragments loaded direct from global (L1-shared across waves) with 1-tile register
// prefetch (ping-pong vA/vB, static indexing). ONE __syncthreads per tile.
// sTP stride 200 B (2-way bank aliasing = free). T13 defer-max; T5 setprio around MFMA.
__global__ __launch_bounds__(256, 2) void attn_kernel(
    const __hip_bfloat16* __restrict__ qpw, const __hip_bfloat16* __restrict__ qpr,
    const __hip_bfloat16* __restrict__ kp, const __hip_bfloat16* __restrict__ vpt,
    const __hip_bfloat16* __restrict__ relp,
    const void* __restrict__ spanv, __hip_bfloat16* __restrict__ attn_out,
    const int* __restrict__ mode) {
  const int md = *mode;
  const int bid = blockIdx.x;
  int rk = (bid >> 3) & 15;
  if (bid & 256) rk ^= 15;               // pair (bid, bid+256) -> complementary lengths
  const int i0 = rk << 7;
  const int bh = (bid & 7) + 8 * (bid >> 7);
  const int b = bh >> 4, h = bh & 15;

  const int tid = threadIdx.x;
  const int lane = tid & 63;
  const int w = tid >> 6;
  const int l31 = lane & 31, hi = lane >> 5;
  const int di = w * 32 + l31;          // this thread's softmax row (block-local)
  const int iRow = i0 + di;

  __shared__ __attribute__((aligned(16))) __hip_bfloat16 sk[2 * 64 * 64];   // 16 KB K double buffer
  __shared__ __attribute__((aligned(16))) __hip_bfloat16 srel[256 * 64];    // 32 KB circular rel band
  __shared__ __attribute__((aligned(16))) short sTP[128 * 100];             // 25.6 KB T rows, stride 200 B

  const int rb = di * 200;              // private row base (bytes), 8B-aligned
  const int sw = l31 & 7;               // swizzle key (== row&7 for all operand reads)

  const __hip_bfloat16* kbase = kp + (size_t)b * KL_ * HID_ + h * D_;
  const __hip_bfloat16* vtb = vpt + ((size_t)(b * H_ + h)) * D_ * KL_;
  const float sv = ldin(spanv, h, md);
  const float svQ = sv * (float)Q_;
  const int pb0 = Q_ - RT_ - i0;
  const int wof = (3 - w) * 32;         // this wave's T-band p-window offset
  const int ntiles = ((M_ + i0 + RT_ - 1) >> 6) + 1;

  const f32x16 z16 = {0.f,0.f,0.f,0.f,0.f,0.f,0.f,0.f,0.f,0.f,0.f,0.f,0.f,0.f,0.f,0.f};

  // ---- q' / q'' fragments: direct global loads of own row (one-time) ----
  short8 qf[4], qrf[4];
  {
    const size_t qofs = ((size_t)(b * Q_ + iRow)) * HID_ + h * D_;
#pragma unroll
    for (int ks = 0; ks < 4; ks++) {
      qf[ks]  = *(const short8*)(qpw + qofs + ks * 16 + hi * 8);
      qrf[ks] = *(const short8*)(qpr + qofs + ks * 16 + hi * 8);
    }
  }

  // ---- V^T fragments for tile 0: direct per-lane global loads (A-operand layout) ----
  short8 vA[8], vB[8];
#pragma unroll
  for (int dt = 0; dt < 2; dt++)
#pragma unroll
    for (int ks = 0; ks < 4; ks++)
      vA[dt * 4 + ks] = *(const short8*)(vtb + (size_t)(dt * 32 + l31) * KL_ + ks * 16 + hi * 8);

  // ---- tile 0 staged via DMA: K into buf0, rel rows 0..191 ----
  {
#pragma unroll
    for (int t = 0; t < 2; t++) {
      int c = (w * 2 + t) * 64 + lane;
      int row = c >> 3;
      int cid = (c & 7) ^ (row & 7);
      async_copy16(kbase + (size_t)row * HID_ + cid * 8, (char*)sk + c * 16);
    }
#pragma unroll
    for (int t = 0; t < 6; t++) {
      int c = (w * 6 + t) * 64 + lane;
      int row = c >> 3;                  // 0..191
      int cid = (c & 7) ^ (row & 7);
      int p = pb0 + row; p = p < KL_ ? p : KL_ - 1;
      async_copy16(relp + (size_t)p * HID_ + h * D_ + cid * 8, (char*)srel + c * 16);
    }
  }

  float mrow = -3e38f, lrow = 0.f, dfrow = 0.f;
  f32x16 oacc[2];
  oacc[0] = z16; oacc[1] = z16;
  int rot = 0;                          // (kt % 4) * 64

  __syncthreads();  // tile-0 DMA drained & visible

  for (int kt = 0; kt < ntiles; kt++) {
    const int j0 = kt * WT_;
    const char* skr = (const char*)sk + (kt & 1) * 8192;
    char* skw = (char*)sk + ((kt + 1) & 1) * 8192;
    const bool pf = (kt + 1 < ntiles);
    int j0n = j0 + WT_; if (j0n > KL_ - WT_) j0n = KL_ - WT_;   // clamp keeps loads in-bounds

    // ---- issue prefetches for tile kt+1: K/rel staging regs + V-next fragments ----
    short8 rK[2], rR[2];
    {
#pragma unroll
      for (int t = 0; t < 2; t++) {
        int c = (w * 2 + t) * 64 + lane;
        int row = c >> 3;
        int cid = (c & 7) ^ (row & 7);
        rK[t] = *(const short8*)(kbase + (size_t)(j0n + row) * HID_ + cid * 8);
        int p = pb0 + kt * 64 + 192 + row; p = p < KL_ ? p : KL_ - 1;
        rR[t] = *(const short8*)(relp + (size_t)p * HID_ + h * D_ + cid * 8);
      }
#pragma unroll
      for (int dt = 0; dt < 2; dt++)
#pragma unroll
        for (int ks = 0; ks < 4; ks++)
          vB[dt * 4 + ks] = *(const short8*)(vtb + (size_t)(dt * 32 + l31) * KL_ + j0n + ks * 16 + hi * 8);
    }
    __builtin_amdgcn_sched_barrier(0);  // pin load issue above the compute phase

    // ---- S^T[j][i] = K . q'^T ----
    __builtin_amdgcn_s_setprio(1);
    f32x16 S[2];
    S[0] = z16; S[1] = z16;
#pragma unroll
    for (int mt = 0; mt < 2; mt++) {
      const char* rowp = skr + (mt * 32 + l31) * 128;
#pragma unroll
      for (int ks = 0; ks < 4; ks++) {
        short8 af = *(const short8*)(rowp + (((ks * 2 + hi) ^ sw) * 16));
        S[mt] = __builtin_amdgcn_mfma_f32_32x32x16_bf16(af, qf[ks], S[mt], 0, 0, 0);
      }
    }

    // ---- T band (wave's 96-row p-window) = rel . q''^T, store into own sTP row ----
#pragma unroll
    for (int mt = 0; mt < 3; mt++) {
      f32x16 T = z16;
      int rr = (wof + mt * 32 + l31 + rot) & 255;
      const char* rowp = (const char*)srel + rr * 128;
#pragma unroll
      for (int ks = 0; ks < 4; ks++) {
        short8 af = *(const short8*)(rowp + (((ks * 2 + hi) ^ sw) * 16));
        T = __builtin_amdgcn_mfma_f32_32x32x16_bf16(af, qrf[ks], T, 0, 0, 0);
      }
#pragma unroll
      for (int r2 = 0; r2 < 4; r2++) {
        short4v pk;
#pragma unroll
        for (int r4 = 0; r4 < 4; r4++) pk[r4] = bfbits(T[r2 * 4 + r4]);
        *(short4v*)((char*)sTP + rb + (mt * 32 + 8 * r2 + 4 * hi) * 2) = pk;
      }
    }
    __builtin_amdgcn_s_setprio(0);

    // ---- gather with per-row shift (own row, in-order DS) ----
    {
      const char* tb2 = (const char*)sTP + rb + (31 - l31 + 4 * hi) * 2;
#pragma unroll
      for (int mt = 0; mt < 2; mt++)
#pragma unroll
        for (int r2 = 0; r2 < 4; r2++)
#pragma unroll
          for (int r4 = 0; r4 < 4; r4++)
            S[mt][r2 * 4 + r4] +=
                __bfloat162float(*(const __hip_bfloat16*)(tb2 + (mt * 32 + 8 * r2 + r4) * 2));
    }

    // ---- logits (log2 units), causal mask only on tiles that can need it ----
    const bool causalT = (j0 + WT_ - 1 - i0) > M_;
    float mnew = mrow;
#pragma unroll
    for (int mt = 0; mt < 2; mt++)
#pragma unroll
      for (int r2 = 0; r2 < 4; r2++)
#pragma unroll
        for (int r4 = 0; r4 < 4; r4++) {
          float v = S[mt][r2 * 4 + r4];
          if (causalT) {
            int j = j0 + mt * 32 + 8 * r2 + 4 * hi + r4;
            if (j - iRow > M_) v = -1e30f;
          }
          S[mt][r2 * 4 + r4] = v;
          mnew = fmaxf(mnew, v);
        }
    mnew = fmaxf(mnew, __shfl_xor(mnew, 32));
    // T13 defer-max: skip rescale while tile max growth <= 8 (P bounded by 2^8)
    if (!__all(mnew - mrow <= 8.f)) {
      const float alpha = fexp2(mrow - mnew);
      mrow = mnew;
      lrow *= alpha; dfrow *= alpha;
#pragma unroll
      for (int dt = 0; dt < 2; dt++)
#pragma unroll
        for (int rg = 0; rg < 16; rg++) oacc[dt][rg] *= alpha;
    }

    // ---- P = exp2(S-m) in-register; span deficit on ramp tiles; permlane assembly ----
    const bool maskT = (j0 + WT_ > M_) && ((float)j0 < (float)M_ + 33.f - svQ);
    short8 paf[4];
#pragma unroll
    for (int mt = 0; mt < 2; mt++) {
      unsigned Pp[4][2];
#pragma unroll
      for (int r2 = 0; r2 < 4; r2++) {
        short4v g;
#pragma unroll
        for (int r4 = 0; r4 < 4; r4++) {
          float pv = fexp2(S[mt][r2 * 4 + r4] - mrow);
          lrow += pv;
          float pm = pv;
          if (maskT) {
            int j = j0 + mt * 32 + 8 * r2 + 4 * hi + r4;
            if (j >= M_) {
              float t0 = (float)(j - M_) + svQ;
              float mk = fminf(fmaxf(t0 * (1.0f / 33.0f), 0.f), 1.f);
              pm = pv * mk;
              dfrow += pv - pm;
            }
          }
          g[r4] = bfbits(pm);
        }
        union { short4v s; unsigned u[2]; } cv; cv.s = g;
        Pp[r2][0] = cv.u[0]; Pp[r2][1] = cv.u[1];
      }
#pragma unroll
      for (int half = 0; half < 2; half++) {
        uint2v rA = __builtin_amdgcn_permlane32_swap(Pp[half * 2][0], Pp[half * 2 + 1][0], false, false);
        uint2v rB = __builtin_amdgcn_permlane32_swap(Pp[half * 2][1], Pp[half * 2 + 1][1], false, false);
        union { unsigned u[4]; short8 s; } asm8;
        asm8.u[0] = rA[0]; asm8.u[1] = rB[0]; asm8.u[2] = rA[1]; asm8.u[3] = rB[1];
        paf[mt * 2 + half] = asm8.s;
      }
    }

    // ---- PV (swapped): A = V^T fragments from registers, B = P (N = own q-row) ----
    __builtin_amdgcn_s_setprio(1);
#pragma unroll
    for (int dt = 0; dt < 2; dt++)
#pragma unroll
      for (int ks = 0; ks < 4; ks++)
        oacc[dt] = __builtin_amdgcn_mfma_f32_32x32x16_bf16(vA[dt * 4 + ks], paf[ks], oacc[dt], 0, 0, 0);
    __builtin_amdgcn_s_setprio(0);

    // ---- commit prefetched K into the other buffer + rel into future circular rows ----
    // (both regions are disjoint from everything read this tile -> no pre-write barrier)
    if (pf) {
#pragma unroll
      for (int t = 0; t < 2; t++) {
        int c = (w * 2 + t) * 64 + lane;
        int row = c >> 3;
        *(short8*)(skw + c * 16) = rK[t];
        int cr = (rot + 192 + row) & 255;
        *(short8*)((char*)srel + cr * 128 + (c & 7) * 16) = rR[t];
      }
    }
    // ---- rotate V fragments (register ping-pong, static indexing) ----
#pragma unroll
    for (int i = 0; i < 8; i++) vA[i] = vB[i];
    rot = (rot + 64) & 255;

    __syncthreads();  // single barrier: commits visible for tile kt+1
  }

  // ---- epilogue: everything is own-row -> scalar denominator, packed b64 stores ----
  lrow += __shfl_xor(lrow, 32);
  dfrow += __shfl_xor(dfrow, 32);
  const float denom = (lrow - dfrow) + 1e-8f * lrow;
  const float rdenom = 1.f / denom;
  __hip_bfloat16* ob = attn_out + ((size_t)(b * Q_ + iRow)) * HID_ + h * D_;
#pragma unroll
  for (int dt = 0; dt < 2; dt++)
#pragma unroll
    for (int r2 = 0; r2 < 4; r2++) {
      short4v o;
#pragma unroll
      for (int r4 = 0; r4 < 4; r4++) o[r4] = bfbits(oacc[dt][r2 * 4 + r4] * rdenom);
      *(short4v*)(ob + dt * 32 + 8 * r2 + 4 * hi) = o;
    }
}

// ---------------- launcher ----------------
extern "C" void kernel_launch(void* const* d_in, const int* in_sizes, int n_in,
                              void* d_out, int out_size, void* d_ws, size_t ws_size,
                              hipStream_t stream) {
  const void* query  = d_in[0];
  const void* memory = d_in[1];
  const void* Wq = d_in[2];
  const void* Wk = d_in[3];
  const void* Wv = d_in[4];
  const void* Wo = d_in[5];
  const void* Wr = d_in[6];
  const void* gmem = d_in[7];
  const void* bmem = d_in[8];
  const void* gq = d_in[9];
  const void* bq = d_in[10];
  const void* rwb = d_in[11];
  const void* rrb = d_in[12];
  const void* spanv = d_in[13];

  char* ws = (char*)d_ws;
  size_t off = 0;
  auto alloc = [&](size_t bytes) -> char* {
    char* p = ws + off;
    off += (bytes + 255) & ~(size_t)255;
    return p;
  };
  int* flag = (int*)alloc(256);
  const size_t SZ_W = (size_t)HID_ * HID_ * 2;
  __hip_bfloat16* wqT = (__hip_bfloat16*)alloc(SZ_W);
  __hip_bfloat16* wkT = (__hip_bfloat16*)alloc(SZ_W);   // contiguous with wvT (SZ_W is 256B-aligned)
  __hip_bfloat16* wvT = (__hip_bfloat16*)alloc(SZ_W);
  __hip_bfloat16* wrT = (__hip_bfloat16*)alloc(SZ_W);
  __hip_bfloat16* woT = (__hip_bfloat16*)alloc(SZ_W);
  __hip_bfloat16* kvln = (__hip_bfloat16*)alloc((size_t)B_ * KL_ * HID_ * 2);
  __hip_bfloat16* qln  = (__hip_bfloat16*)alloc((size_t)B_ * Q_ * HID_ * 2);
  __hip_bfloat16* pe   = (__hip_bfloat16*)alloc((size_t)KL_ * HID_ * 2);
  __hip_bfloat16* qpw  = (__hip_bfloat16*)alloc((size_t)B_ * Q_ * HID_ * 2);
  __hip_bfloat16* qpr  = (__hip_bfloat16*)alloc((size_t)B_ * Q_ * HID_ * 2);
  __hip_bfloat16* kpb  = (__hip_bfloat16*)alloc((size_t)B_ * KL_ * HID_ * 2);
  __hip_bfloat16* vptb = (__hip_bfloat16*)alloc((size_t)B_ * KL_ * HID_ * 2);  // V, transposed per-head
  __hip_bfloat16* relp = (__hip_bfloat16*)alloc((size_t)KL_ * HID_ * 2);
  __hip_bfloat16* aout = (__hip_bfloat16*)alloc((size_t)B_ * Q_ * HID_ * 2);

  dim3 tb(256);
  detect_kernel<<<dim3(1), tb, 0, stream>>>((const unsigned int*)query, flag);

  wtpe_kernel<<<dim3(16, 16, 21), tb, 0, stream>>>(Wq, Wk, Wv, Wr, Wo,
                                                   wqT, wkT, wvT, wrT, woT, pe, flag);

  ln_kernel<<<dim3(B_ * KL_ + B_ * Q_), tb, 0, stream>>>(memory, query, gmem, bmem, gq, bq,
                                                         kvln, qln, flag);

  gemm_q<<<dim3(B_ * Q_ / 128, HID_ / 128), tb, 0, stream>>>(qln, wqT, rwb, rrb, qpw, qpr, flag);
  gemm_dualv<<<dim3(B_ * KL_ / 128, 2 * HID_ / 128), tb, 0, stream>>>(kvln, wkT, kpb, vptb);
  gemm_bt128<<<dim3(KL_ / 128, HID_ / 128), tb, 0, stream>>>(pe, wrT, relp, 1.0f);

  attn_kernel<<<dim3((Q_ / RT_) * H_ * B_), tb, 0, stream>>>(qpw, qpr, kpb, vptb, relp, spanv, aout, flag);

  gemm_out<<<dim3(B_ * Q_ / 128, HID_ / 128), tb, 0, stream>>>(aout, woT, d_out, flag);

  (void)in_sizes; (void)n_in; (void)out_size; (void)ws_size;
}

// Round 8
// 476.115 us; speedup vs baseline: 1.0797x; 1.0797x over previous
//
#include <hip/hip_runtime.h>
#include <hip/hip_bf16.h>
#include <math.h>

#define B_   2
#define Q_   2048
#define M_   2048
#define H_   16
#define D_   64
#define HID_ 1024
#define KL_  4096
#define RT_  128     // q rows per attention block
#define WT_  64      // k cols per attention tile
#define LSCL 0.022542110013890053f   // log2(e)/64 — logits kept in log2 units

typedef short short8 __attribute__((ext_vector_type(8)));
typedef short short4v __attribute__((ext_vector_type(4)));
typedef float f32x4 __attribute__((ext_vector_type(4)));
typedef float f32x16 __attribute__((ext_vector_type(16)));
typedef unsigned int uint2v __attribute__((ext_vector_type(2)));

__device__ __forceinline__ void async_copy16(const void* g, void* l) {
  __builtin_amdgcn_global_load_lds((const __attribute__((address_space(1))) unsigned int*)g,
                                   (__attribute__((address_space(3))) unsigned int*)l,
                                   16, 0, 0);
}

// read input element i as float, md=1 -> fp32 buffer, md=0 -> bf16 buffer
__device__ __forceinline__ float ldin(const void* p, size_t i, int md) {
  return md ? ((const float*)p)[i] : __bfloat162float(((const __hip_bfloat16*)p)[i]);
}

__device__ __forceinline__ short bfbits(float v) {
  __hip_bfloat16 t = __float2bfloat16(v);
  return *(short*)&t;
}

// fast 2^x: lowers to v_exp_f32 (HW computes 2^x natively)
__device__ __forceinline__ float fexp2(float x) { return exp2f(x); }

// ---------------- dtype detector: writes 1 if inputs are fp32, else 0 ----------------
__global__ __launch_bounds__(256) void detect_kernel(const unsigned int* __restrict__ q,
                                                     int* __restrict__ flag) {
  __shared__ int cnt;
  if (threadIdx.x == 0) cnt = 0;
  __syncthreads();
  int ins = 0;
#pragma unroll
  for (int i = 0; i < 4; i++) {
    unsigned int u = q[threadIdx.x * 4 + i];
    int e0 = (int)((u >> 7) & 0xffu);
    int e1 = (int)((u >> 23) & 0xffu);
    if (e0 == 0xff || e0 < 102 || e0 > 140) ins++;
    if (e1 == 0xff || e1 < 102 || e1 > 140) ins++;
  }
  atomicAdd(&cnt, ins);
  __syncthreads();
  if (threadIdx.x == 0) *flag = (cnt > 512) ? 1 : 0;
}

// ---------------- fused: 5 weight transposes (z<5) + sinusoidal pos-emb (z>=5) ----------------
__global__ __launch_bounds__(256) void wtpe_kernel(
    const void* __restrict__ s0, const void* __restrict__ s1, const void* __restrict__ s2,
    const void* __restrict__ s3, const void* __restrict__ s4,
    __hip_bfloat16* __restrict__ d0, __hip_bfloat16* __restrict__ d1,
    __hip_bfloat16* __restrict__ d2, __hip_bfloat16* __restrict__ d3,
    __hip_bfloat16* __restrict__ d4, __hip_bfloat16* __restrict__ pe,
    const int* __restrict__ mode) {
  const int tid = threadIdx.x;
  if (blockIdx.z >= 5) {
    // pos-emb: positions K-1..0
    const int p = (blockIdx.z - 5) * 256 + blockIdx.y * 16 + blockIdx.x;
    const float pos = (float)(KL_ - 1 - p);
#pragma unroll
    for (int i = 0; i < 4; i++) {
      int c = tid * 4 + i;
      int f = (c < 512) ? c : c - 512;
      float invf = fexp2(-(float)f * (13.287712379549449f / 512.0f));
      float a = pos * invf;
      float v = (c < 512) ? __sinf(a) : __cosf(a);
      pe[(size_t)p * HID_ + c] = __float2bfloat16(v);
    }
    return;
  }
  const int md = *mode;
  const void* src; __hip_bfloat16* dst;
  switch (blockIdx.z) {
    case 0: src = s0; dst = d0; break;
    case 1: src = s1; dst = d1; break;
    case 2: src = s2; dst = d2; break;
    case 3: src = s3; dst = d3; break;
    default: src = s4; dst = d4; break;
  }
  const int r0 = blockIdx.x * 64, c0 = blockIdx.y * 64;
  __shared__ __hip_bfloat16 t[64][65];
  const int col = tid & 63, r4 = tid >> 6;
#pragma unroll
  for (int i = 0; i < 16; i++)
    t[r4 + i * 4][col] = __float2bfloat16(ldin(src, (size_t)(r0 + r4 + i * 4) * HID_ + c0 + col, md));
  __syncthreads();
#pragma unroll
  for (int i = 0; i < 16; i++)
    dst[(size_t)(c0 + r4 + i * 4) * HID_ + r0 + col] = t[col][r4 + i * 4];
}

// ---------------- fused LayerNorm: rows [0,B*KL) = concat(mem,query); rows >= B*KL = query ----------------
__global__ __launch_bounds__(256) void ln_kernel(
    const void* __restrict__ mem, const void* __restrict__ qry,
    const void* __restrict__ gmem, const void* __restrict__ bmem,
    const void* __restrict__ gq, const void* __restrict__ bq,
    __hip_bfloat16* __restrict__ kvout, __hip_bfloat16* __restrict__ qout,
    const int* __restrict__ mode) {
  const int md = *mode;
  const int row = blockIdx.x;  // 0..B*KL + B*Q - 1
  const void* src;
  const void* gamma; const void* beta;
  size_t base;
  __hip_bfloat16* dst;
  if (row < B_ * KL_) {
    const int b = row / KL_, j = row % KL_;
    if (j < M_) { src = mem; base = ((size_t)b * M_ + j) * HID_; }
    else        { src = qry; base = ((size_t)b * Q_ + (j - M_)) * HID_; }
    gamma = gmem; beta = bmem;
    dst = kvout + (size_t)row * HID_;
  } else {
    const int r = row - B_ * KL_;
    src = qry; base = (size_t)r * HID_;
    gamma = gq; beta = bq;
    dst = qout + (size_t)r * HID_;
  }
  const int tid = threadIdx.x;
  float x[4];
  float s = 0.f, ss = 0.f;
#pragma unroll
  for (int i = 0; i < 4; i++) {
    x[i] = ldin(src, base + i * 256 + tid, md);
    s += x[i]; ss += x[i] * x[i];
  }
#pragma unroll
  for (int o = 32; o > 0; o >>= 1) { s += __shfl_down(s, o); ss += __shfl_down(ss, o); }
  __shared__ float red[8];
  if ((tid & 63) == 0) { red[(tid >> 6) * 2] = s; red[(tid >> 6) * 2 + 1] = ss; }
  __syncthreads();
  float ts = 0.f, tss = 0.f;
#pragma unroll
  for (int i = 0; i < 4; i++) { ts += red[i * 2]; tss += red[i * 2 + 1]; }
  const float mu = ts * (1.f / 1024.f);
  const float var = tss * (1.f / 1024.f) - mu * mu;
  const float rs = rsqrtf(var + 1e-3f);
#pragma unroll
  for (int i = 0; i < 4; i++) {
    int c = i * 256 + tid;
    dst[c] = __float2bfloat16((x[i] - mu) * rs * ldin(gamma, c, md) + ldin(beta, c, md));
  }
}

// ---------------- GEMM core: C = A @ BT^T (both bf16, K=1024), 128x128 tile, BK=64 ----------------
template <int WRITE_MODE_SWITCH>
__device__ __forceinline__ void gemm_body(const __hip_bfloat16* __restrict__ A,
                                          const __hip_bfloat16* __restrict__ BT,
                                          void* __restrict__ C, int md, float scl) {
  __shared__ __attribute__((aligned(16))) __hip_bfloat16 sA[128 * 64];
  __shared__ __attribute__((aligned(16))) __hip_bfloat16 sB[128 * 64];
  const int tid = threadIdx.x;
  const int lane = tid & 63;
  const int w = tid >> 6;
  const int quad = lane >> 4, l16 = lane & 15;
  const int m0 = blockIdx.x * 128;
  const int n0 = blockIdx.y * 128;
  const int wm = (w >> 1) * 64, wn = (w & 1) * 64;
  const f32x4 fz = {0.f, 0.f, 0.f, 0.f};

  f32x4 acc[4][4];
#pragma unroll
  for (int i = 0; i < 4; i++)
#pragma unroll
    for (int j = 0; j < 4; j++) acc[i][j] = fz;

  for (int kk = 0; kk < HID_ / 64; kk++) {
    const int k0 = kk * 64;
    __syncthreads();
#pragma unroll
    for (int t = 0; t < 4; t++) {
      int c = (w * 4 + t) * 64 + lane;
      int row = c >> 3;
      int cid = (c & 7) ^ (row & 7);
      async_copy16(A + (size_t)(m0 + row) * HID_ + k0 + cid * 8, (char*)sA + c * 16);
      async_copy16(BT + (size_t)(n0 + row) * HID_ + k0 + cid * 8, (char*)sB + c * 16);
    }
    __syncthreads();
#pragma unroll
    for (int half = 0; half < 2; half++) {
      short8 af[4], bf[4];
#pragma unroll
      for (int mt = 0; mt < 4; mt++) {
        int r = wm + mt * 16 + l16;
        af[mt] = *(const short8*)((const char*)sA + r * 128 + (((half * 4 + quad) ^ (r & 7)) * 16));
      }
#pragma unroll
      for (int nt = 0; nt < 4; nt++) {
        int r = wn + nt * 16 + l16;
        bf[nt] = *(const short8*)((const char*)sB + r * 128 + (((half * 4 + quad) ^ (r & 7)) * 16));
      }
#pragma unroll
      for (int mt = 0; mt < 4; mt++)
#pragma unroll
        for (int nt = 0; nt < 4; nt++)
          acc[mt][nt] = __builtin_amdgcn_mfma_f32_16x16x32_bf16(af[mt], bf[nt], acc[mt][nt], 0, 0, 0);
    }
  }
#pragma unroll
  for (int mt = 0; mt < 4; mt++)
#pragma unroll
    for (int nt = 0; nt < 4; nt++)
#pragma unroll
      for (int rg = 0; rg < 4; rg++) {
        int r = m0 + wm + mt * 16 + quad * 4 + rg;
        int cc = n0 + wn + nt * 16 + l16;
        size_t idx = (size_t)r * HID_ + cc;
        if (WRITE_MODE_SWITCH && md) ((float*)C)[idx] = acc[mt][nt][rg];
        else ((__hip_bfloat16*)C)[idx] = __float2bfloat16(acc[mt][nt][rg] * scl);
      }
}

__global__ __launch_bounds__(256) void gemm_bt128(const __hip_bfloat16* __restrict__ A,
                                                  const __hip_bfloat16* __restrict__ BT,
                                                  __hip_bfloat16* __restrict__ C, float scl) {
  gemm_body<0>(A, BT, (void*)C, 0, scl);
}

__global__ __launch_bounds__(256) void gemm_out(const __hip_bfloat16* __restrict__ A,
                                                const __hip_bfloat16* __restrict__ BT,
                                                void* __restrict__ C,
                                                const int* __restrict__ mode) {
  gemm_body<1>(A, BT, C, *mode, 1.0f);
}

// ---- q-projection GEMM with dual-bias epilogue: qw=(acc+rwb)*LSCL, qr=(acc+rrb)*LSCL (BK=64) ----
__global__ __launch_bounds__(256) void gemm_q(const __hip_bfloat16* __restrict__ A,
                                              const __hip_bfloat16* __restrict__ BT,
                                              const void* __restrict__ rwb,
                                              const void* __restrict__ rrb,
                                              __hip_bfloat16* __restrict__ qw,
                                              __hip_bfloat16* __restrict__ qr,
                                              const int* __restrict__ mode) {
  const int md = *mode;
  __shared__ __attribute__((aligned(16))) __hip_bfloat16 sA[128 * 64];
  __shared__ __attribute__((aligned(16))) __hip_bfloat16 sB[128 * 64];
  const int tid = threadIdx.x;
  const int lane = tid & 63;
  const int w = tid >> 6;
  const int quad = lane >> 4, l16 = lane & 15;
  const int m0 = blockIdx.x * 128;
  const int n0 = blockIdx.y * 128;
  const int wm = (w >> 1) * 64, wn = (w & 1) * 64;
  const f32x4 fz = {0.f, 0.f, 0.f, 0.f};

  f32x4 acc[4][4];
#pragma unroll
  for (int i = 0; i < 4; i++)
#pragma unroll
    for (int j = 0; j < 4; j++) acc[i][j] = fz;

  for (int kk = 0; kk < HID_ / 64; kk++) {
    const int k0 = kk * 64;
    __syncthreads();
#pragma unroll
    for (int t = 0; t < 4; t++) {
      int c = (w * 4 + t) * 64 + lane;
      int row = c >> 3;
      int cid = (c & 7) ^ (row & 7);
      async_copy16(A + (size_t)(m0 + row) * HID_ + k0 + cid * 8, (char*)sA + c * 16);
      async_copy16(BT + (size_t)(n0 + row) * HID_ + k0 + cid * 8, (char*)sB + c * 16);
    }
    __syncthreads();
#pragma unroll
    for (int half = 0; half < 2; half++) {
      short8 af[4], bf[4];
#pragma unroll
      for (int mt = 0; mt < 4; mt++) {
        int r = wm + mt * 16 + l16;
        af[mt] = *(const short8*)((const char*)sA + r * 128 + (((half * 4 + quad) ^ (r & 7)) * 16));
      }
#pragma unroll
      for (int nt = 0; nt < 4; nt++) {
        int r = wn + nt * 16 + l16;
        bf[nt] = *(const short8*)((const char*)sB + r * 128 + (((half * 4 + quad) ^ (r & 7)) * 16));
      }
#pragma unroll
      for (int mt = 0; mt < 4; mt++)
#pragma unroll
        for (int nt = 0; nt < 4; nt++)
          acc[mt][nt] = __builtin_amdgcn_mfma_f32_16x16x32_bf16(af[mt], bf[nt], acc[mt][nt], 0, 0, 0);
    }
  }
  float bw[4], br[4];
#pragma unroll
  for (int nt = 0; nt < 4; nt++) {
    int cc = n0 + wn + nt * 16 + l16;
    bw[nt] = ldin(rwb, cc, md);
    br[nt] = ldin(rrb, cc, md);
  }
#pragma unroll
  for (int mt = 0; mt < 4; mt++)
#pragma unroll
    for (int nt = 0; nt < 4; nt++)
#pragma unroll
      for (int rg = 0; rg < 4; rg++) {
        int r = m0 + wm + mt * 16 + quad * 4 + rg;
        int cc = n0 + wn + nt * 16 + l16;
        size_t idx = (size_t)r * HID_ + cc;
        float a = acc[mt][nt][rg];
        qw[idx] = __float2bfloat16((a + bw[nt]) * LSCL);
        qr[idx] = __float2bfloat16((a + br[nt]) * LSCL);
      }
}

// ---- dual GEMM: BT = contiguous [wkT; wvT]; K-half -> kpb (row-major), V-half -> vpt
// (transposed per-head layout [b][h][d][j]). BK=64; transpose scratch sT unioned with
// sA/sB (epilogue-only use, barrier-guarded) -> 34.8 KB LDS total. ----
__global__ __launch_bounds__(256) void gemm_dualv(const __hip_bfloat16* __restrict__ A,
                                                  const __hip_bfloat16* __restrict__ BT,
                                                  __hip_bfloat16* __restrict__ C0,
                                                  __hip_bfloat16* __restrict__ vpt) {
  __shared__ __attribute__((aligned(16))) char smem[128 * 136 * 2];  // 34816 B >= sA+sB (32768)
  __hip_bfloat16* sA = (__hip_bfloat16*)smem;
  __hip_bfloat16* sB = (__hip_bfloat16*)(smem + 16384);
  short* sT = (short*)smem;
  const int tid = threadIdx.x;
  const int lane = tid & 63;
  const int w = tid >> 6;
  const int quad = lane >> 4, l16 = lane & 15;
  const int m0 = blockIdx.x * 128;
  const int n0 = blockIdx.y * 128;  // 0..1920
  const int wm = (w >> 1) * 64, wn = (w & 1) * 64;
  const f32x4 fz = {0.f, 0.f, 0.f, 0.f};

  f32x4 acc[4][4];
#pragma unroll
  for (int i = 0; i < 4; i++)
#pragma unroll
    for (int j = 0; j < 4; j++) acc[i][j] = fz;

  for (int kk = 0; kk < HID_ / 64; kk++) {
    const int k0 = kk * 64;
    __syncthreads();
#pragma unroll
    for (int t = 0; t < 4; t++) {
      int c = (w * 4 + t) * 64 + lane;
      int row = c >> 3;
      int cid = (c & 7) ^ (row & 7);
      async_copy16(A + (size_t)(m0 + row) * HID_ + k0 + cid * 8, (char*)sA + c * 16);
      async_copy16(BT + (size_t)(n0 + row) * HID_ + k0 + cid * 8, (char*)sB + c * 16);
    }
    __syncthreads();
#pragma unroll
    for (int half = 0; half < 2; half++) {
      short8 af[4], bf[4];
#pragma unroll
      for (int mt = 0; mt < 4; mt++) {
        int r = wm + mt * 16 + l16;
        af[mt] = *(const short8*)((const char*)sA + r * 128 + (((half * 4 + quad) ^ (r & 7)) * 16));
      }
#pragma unroll
      for (int nt = 0; nt < 4; nt++) {
        int r = wn + nt * 16 + l16;
        bf[nt] = *(const short8*)((const char*)sB + r * 128 + (((half * 4 + quad) ^ (r & 7)) * 16));
      }
#pragma unroll
      for (int mt = 0; mt < 4; mt++)
#pragma unroll
        for (int nt = 0; nt < 4; nt++)
          acc[mt][nt] = __builtin_amdgcn_mfma_f32_16x16x32_bf16(af[mt], bf[nt], acc[mt][nt], 0, 0, 0);
    }
  }
  if (n0 < HID_) {
    // K half: row-major write
#pragma unroll
    for (int mt = 0; mt < 4; mt++)
#pragma unroll
      for (int nt = 0; nt < 4; nt++)
#pragma unroll
        for (int rg = 0; rg < 4; rg++) {
          int r = m0 + wm + mt * 16 + quad * 4 + rg;
          int cc = n0 + wn + nt * 16 + l16;
          C0[(size_t)r * HID_ + cc] = __float2bfloat16(acc[mt][nt][rg]);
        }
  } else {
    // V half: transpose through sT (unioned with sA/sB) -> vpt[((b*H+h)*D+d)*KL + j]
    __syncthreads();  // all MFMA LDS reads done before sT overwrites sA/sB space
#pragma unroll
    for (int mt = 0; mt < 4; mt++)
#pragma unroll
      for (int nt = 0; nt < 4; nt++) {
        int r = wm + mt * 16 + quad * 4;   // local j base (rg 0..3 consecutive)
        int cc = wn + nt * 16 + l16;       // local col
        short4v pk;
#pragma unroll
        for (int rg = 0; rg < 4; rg++) pk[rg] = bfbits(acc[mt][nt][rg]);
        *(short4v*)&sT[cc * 136 + r] = pk;
      }
    __syncthreads();
    const int b = m0 >> 12;            // 4096 rows per batch
    const int j0g = m0 & (KL_ - 1);
    const int cg0 = n0 - HID_;
#pragma unroll
    for (int it = 0; it < 16; it++) {
      int cc = it * 8 + w * 2 + (lane >> 5);
      int jj = (lane & 31) * 4;
      int cg = cg0 + cc;
      int h = cg >> 6, d = cg & 63;
      short4v v = *(const short4v*)&sT[cc * 136 + jj];
      *(short4v*)(vpt + (((size_t)(b * H_ + h)) * D_ + d) * KL_ + j0g + jj) = v;
    }
  }
}

// ---------------- fused relative attention, 32x32 MFMA (round-5 structure + tree reductions) ----------------
// grid 512 (all-resident: 2 blocks/CU, rank-flipped so each CU's pair is long+short),
// block 256 (4 waves x 32 q-rows each). RT=128, WT=64. mfma_f32_32x32x16_bf16 for
// S (K.q'^T), T (rel.q''^T) and PV (V^T.P). PV operands swapped so output cols = own
// q-row -> scalar alpha/denominator. P assembled in-register via permlane32_swap.
// srel: 192-row circular band rotated 64 rows/tile. sTP stride 200 B -> 16-bank spread
// (2-way aliasing = free); T13 defer-max; T5 setprio; fmax/lrow as trees (dep-chain cut).
__global__ __launch_bounds__(256, 2) void attn_kernel(
    const __hip_bfloat16* __restrict__ qpw, const __hip_bfloat16* __restrict__ qpr,
    const __hip_bfloat16* __restrict__ kp, const __hip_bfloat16* __restrict__ vpt,
    const __hip_bfloat16* __restrict__ relp,
    const void* __restrict__ spanv, __hip_bfloat16* __restrict__ attn_out,
    const int* __restrict__ mode) {
  const int md = *mode;
  const int bid = blockIdx.x;
  int rk = (bid >> 3) & 15;
  if (bid & 256) rk ^= 15;               // pair (bid, bid+256) -> complementary lengths
  const int i0 = rk << 7;
  const int bh = (bid & 7) + 8 * (bid >> 7);
  const int b = bh >> 4, h = bh & 15;

  const int tid = threadIdx.x;
  const int lane = tid & 63;
  const int w = tid >> 6;
  const int l31 = lane & 31, hi = lane >> 5;
  const int di = w * 32 + l31;          // this thread's softmax row (block-local)
  const int iRow = i0 + di;

  __shared__ __attribute__((aligned(16))) __hip_bfloat16 sk[64 * 64];     // 8 KB K tile
  __shared__ __attribute__((aligned(16))) __hip_bfloat16 srel[192 * 64];  // 24 KB circular rel band
  __shared__ __attribute__((aligned(16))) __hip_bfloat16 svt[64 * 64];    // 8 KB V^T tile
  __shared__ __attribute__((aligned(16))) short sTP[128 * 100];           // 25 KB T rows, stride 200 B

  const int rb = di * 200;              // private row base (bytes), 8B-aligned
  const int sw = l31 & 7;               // swizzle key (== row&7 for all operand reads)

  const __hip_bfloat16* kbase = kp + (size_t)b * KL_ * HID_ + h * D_;
  const __hip_bfloat16* vtb = vpt + ((size_t)(b * H_ + h)) * D_ * KL_;
  const float sv = ldin(spanv, h, md);
  const float svQ = sv * (float)Q_;
  const int pb0 = Q_ - RT_ - i0;
  const int wof = (3 - w) * 32;         // this wave's T-band p-window offset
  const int ntiles = ((M_ + i0 + RT_ - 1) >> 6) + 1;

  const f32x16 z16 = {0.f,0.f,0.f,0.f,0.f,0.f,0.f,0.f,0.f,0.f,0.f,0.f,0.f,0.f,0.f,0.f};

  // ---- q' / q'' fragments: direct global loads of own row (one-time) ----
  short8 qf[4], qrf[4];
  {
    const size_t qofs = ((size_t)(b * Q_ + iRow)) * HID_ + h * D_;
#pragma unroll
    for (int ks = 0; ks < 4; ks++) {
      qf[ks]  = *(const short8*)(qpw + qofs + ks * 16 + hi * 8);
      qrf[ks] = *(const short8*)(qpr + qofs + ks * 16 + hi * 8);
    }
  }

  // ---- tile 0 staged via DMA (K, full 192-row rel band, V^T) ----
  {
#pragma unroll
    for (int t = 0; t < 2; t++) {
      int c = (w * 2 + t) * 64 + lane;
      int row = c >> 3;
      int cid = (c & 7) ^ (row & 7);
      async_copy16(kbase + (size_t)row * HID_ + cid * 8, (char*)sk + c * 16);
      async_copy16(vtb + (size_t)row * KL_ + cid * 8, (char*)svt + c * 16);
    }
#pragma unroll
    for (int t = 0; t < 6; t++) {
      int c = (w * 6 + t) * 64 + lane;
      int row = c >> 3;                  // 0..191
      int cid = (c & 7) ^ (row & 7);
      int p = pb0 + row; p = p < KL_ ? p : KL_ - 1;
      async_copy16(relp + (size_t)p * HID_ + h * D_ + cid * 8, (char*)srel + c * 16);
    }
  }

  float mrow = -3e38f, lrow = 0.f, dfrow = 0.f;
  f32x16 oacc[2];
  oacc[0] = z16; oacc[1] = z16;
  int rot = 0;                          // (kt % 3) * 64

  for (int kt = 0; kt < ntiles; kt++) {
    const int j0 = kt * WT_;

    __syncthreads();  // B: tile kt staging (DMA or ds_writes) visible

    // ---- prefetch tile kt+1 into registers (issued before compute; committed after) ----
    short8 rK[2], rR[2], rV[2];
    const bool pf = (kt + 1 < ntiles);
    {
      int j0n = j0 + WT_; if (j0n > KL_ - WT_) j0n = KL_ - WT_;
#pragma unroll
      for (int t = 0; t < 2; t++) {
        int c = (w * 2 + t) * 64 + lane;
        int row = c >> 3;
        int cid = (c & 7) ^ (row & 7);
        rK[t] = *(const short8*)(kbase + (size_t)(j0n + row) * HID_ + cid * 8);
        rV[t] = *(const short8*)(vtb + (size_t)row * KL_ + j0n + cid * 8);
        int p = pb0 + (kt + 1) * 64 + 128 + row; p = p < KL_ ? p : KL_ - 1;
        rR[t] = *(const short8*)(relp + (size_t)p * HID_ + h * D_ + cid * 8);
      }
    }
    __builtin_amdgcn_sched_barrier(0);  // pin load issue above the compute phase

    // ---- S^T[j][i] = K . q'^T ----
    __builtin_amdgcn_s_setprio(1);
    f32x16 S[2];
    S[0] = z16; S[1] = z16;
#pragma unroll
    for (int mt = 0; mt < 2; mt++) {
      const char* rowp = (const char*)sk + (mt * 32 + l31) * 128;
#pragma unroll
      for (int ks = 0; ks < 4; ks++) {
        short8 af = *(const short8*)(rowp + (((ks * 2 + hi) ^ sw) * 16));
        S[mt] = __builtin_amdgcn_mfma_f32_32x32x16_bf16(af, qf[ks], S[mt], 0, 0, 0);
      }
    }

    // ---- T band (wave's 96-row p-window) = rel . q''^T, store into own sTP row ----
#pragma unroll
    for (int mt = 0; mt < 3; mt++) {
      f32x16 T = z16;
      int rr = wof + mt * 32 + l31 + rot; if (rr >= 192) rr -= 192;
      const char* rowp = (const char*)srel + rr * 128;
#pragma unroll
      for (int ks = 0; ks < 4; ks++) {
        short8 af = *(const short8*)(rowp + (((ks * 2 + hi) ^ sw) * 16));
        T = __builtin_amdgcn_mfma_f32_32x32x16_bf16(af, qrf[ks], T, 0, 0, 0);
      }
#pragma unroll
      for (int r2 = 0; r2 < 4; r2++) {
        short4v pk;
#pragma unroll
        for (int r4 = 0; r4 < 4; r4++) pk[r4] = bfbits(T[r2 * 4 + r4]);
        *(short4v*)((char*)sTP + rb + (mt * 32 + 8 * r2 + 4 * hi) * 2) = pk;
      }
    }
    __builtin_amdgcn_s_setprio(0);

    // ---- gather with per-row shift (own row, in-order DS) ----
    {
      const char* tb2 = (const char*)sTP + rb + (31 - l31 + 4 * hi) * 2;
#pragma unroll
      for (int mt = 0; mt < 2; mt++)
#pragma unroll
        for (int r2 = 0; r2 < 4; r2++)
#pragma unroll
          for (int r4 = 0; r4 < 4; r4++)
            S[mt][r2 * 4 + r4] +=
                __bfloat162float(*(const __hip_bfloat16*)(tb2 + (mt * 32 + 8 * r2 + r4) * 2));
    }

    // ---- logits (log2 units), causal mask only on tiles that can need it ----
    const bool causalT = (j0 + WT_ - 1 - i0) > M_;
    if (causalT) {
#pragma unroll
      for (int mt = 0; mt < 2; mt++)
#pragma unroll
        for (int r2 = 0; r2 < 4; r2++)
#pragma unroll
          for (int r4 = 0; r4 < 4; r4++) {
            int j = j0 + mt * 32 + 8 * r2 + 4 * hi + r4;
            if (j - iRow > M_) S[mt][r2 * 4 + r4] = -1e30f;
          }
    }
    // tree max: depth ~6 instead of 32-deep serial chain (clang fuses to v_max3)
    float m8[8];
#pragma unroll
    for (int g = 0; g < 8; g++) {
      int mt = g >> 2, r2 = g & 3;
      m8[g] = fmaxf(fmaxf(S[mt][r2 * 4 + 0], S[mt][r2 * 4 + 1]),
                    fmaxf(S[mt][r2 * 4 + 2], S[mt][r2 * 4 + 3]));
    }
    float mnew = fmaxf(mrow,
        fmaxf(fmaxf(fmaxf(m8[0], m8[1]), fmaxf(m8[2], m8[3])),
              fmaxf(fmaxf(m8[4], m8[5]), fmaxf(m8[6], m8[7]))));
    mnew = fmaxf(mnew, __shfl_xor(mnew, 32));
    // T13 defer-max: skip rescale while tile max growth <= 8 (P bounded by 2^8)
    if (!__all(mnew - mrow <= 8.f)) {
      const float alpha = fexp2(mrow - mnew);
      mrow = mnew;
      lrow *= alpha; dfrow *= alpha;
#pragma unroll
      for (int dt = 0; dt < 2; dt++)
#pragma unroll
        for (int rg = 0; rg < 16; rg++) oacc[dt][rg] *= alpha;
    }

    // ---- P = exp2(S-m) in-register; span deficit on ramp tiles; permlane assembly ----
    const bool maskT = (j0 + WT_ > M_) && ((float)j0 < (float)M_ + 33.f - svQ);
    short8 paf[4];
#pragma unroll
    for (int mt = 0; mt < 2; mt++) {
      unsigned Pp[4][2];
#pragma unroll
      for (int r2 = 0; r2 < 4; r2++) {
        short4v g;
        float pvv[4];
#pragma unroll
        for (int r4 = 0; r4 < 4; r4++) {
          float pv = fexp2(S[mt][r2 * 4 + r4] - mrow);
          pvv[r4] = pv;
          float pm = pv;
          if (maskT) {
            int j = j0 + mt * 32 + 8 * r2 + 4 * hi + r4;
            if (j >= M_) {
              float t0 = (float)(j - M_) + svQ;
              float mk = fminf(fmaxf(t0 * (1.0f / 33.0f), 0.f), 1.f);
              pm = pv * mk;
              dfrow += pv - pm;
            }
          }
          g[r4] = bfbits(pm);
        }
        lrow += (pvv[0] + pvv[1]) + (pvv[2] + pvv[3]);  // tree partial, short dep chain
        union { short4v s; unsigned u[2]; } cv; cv.s = g;
        Pp[r2][0] = cv.u[0]; Pp[r2][1] = cv.u[1];
      }
#pragma unroll
      for (int half = 0; half < 2; half++) {
        uint2v rA = __builtin_amdgcn_permlane32_swap(Pp[half * 2][0], Pp[half * 2 + 1][0], false, false);
        uint2v rB = __builtin_amdgcn_permlane32_swap(Pp[half * 2][1], Pp[half * 2 + 1][1], false, false);
        union { unsigned u[4]; short8 s; } asm8;
        asm8.u[0] = rA[0]; asm8.u[1] = rB[0]; asm8.u[2] = rA[1]; asm8.u[3] = rB[1];
        paf[mt * 2 + half] = asm8.s;
      }
    }

    // ---- PV (swapped): A = V^T rows (M=d), B = P (N = own q-row) ----
    __builtin_amdgcn_s_setprio(1);
#pragma unroll
    for (int dt = 0; dt < 2; dt++) {
      const char* rowp = (const char*)svt + (dt * 32 + l31) * 128;
#pragma unroll
      for (int ks = 0; ks < 4; ks++) {
        short8 bfv = *(const short8*)(rowp + (((ks * 2 + hi) ^ sw) * 16));
        oacc[dt] = __builtin_amdgcn_mfma_f32_32x32x16_bf16(bfv, paf[ks], oacc[dt], 0, 0, 0);
      }
    }
    __builtin_amdgcn_s_setprio(0);

    __syncthreads();  // A: all LDS consumers of tile kt done

    // ---- commit prefetched tile kt+1 to LDS (vmcnt drain here, after compute) ----
    if (pf) {
#pragma unroll
      for (int t = 0; t < 2; t++) {
        int c = (w * 2 + t) * 64 + lane;
        int row = c >> 3;
        *(short8*)((char*)sk + c * 16) = rK[t];
        *(short8*)((char*)svt + c * 16) = rV[t];
        *(short8*)((char*)srel + (rot + row) * 128 + (c & 7) * 16) = rR[t];
      }
    }
    rot += 64; if (rot == 192) rot = 0;
  }

  // ---- epilogue: everything is own-row -> scalar denominator, packed b64 stores ----
  lrow += __shfl_xor(lrow, 32);
  dfrow += __shfl_xor(dfrow, 32);
  const float denom = (lrow - dfrow) + 1e-8f * lrow;
  const float rdenom = 1.f / denom;
  __hip_bfloat16* ob = attn_out + ((size_t)(b * Q_ + iRow)) * HID_ + h * D_;
#pragma unroll
  for (int dt = 0; dt < 2; dt++)
#pragma unroll
    for (int r2 = 0; r2 < 4; r2++) {
      short4v o;
#pragma unroll
      for (int r4 = 0; r4 < 4; r4++) o[r4] = bfbits(oacc[dt][r2 * 4 + r4] * rdenom);
      *(short4v*)(ob + dt * 32 + 8 * r2 + 4 * hi) = o;
    }
}

// ---------------- launcher ----------------
extern "C" void kernel_launch(void* const* d_in, const int* in_sizes, int n_in,
                              void* d_out, int out_size, void* d_ws, size_t ws_size,
                              hipStream_t stream) {
  const void* query  = d_in[0];
  const void* memory = d_in[1];
  const void* Wq = d_in[2];
  const void* Wk = d_in[3];
  const void* Wv = d_in[4];
  const void* Wo = d_in[5];
  const void* Wr = d_in[6];
  const void* gmem = d_in[7];
  const void* bmem = d_in[8];
  const void* gq = d_in[9];
  const void* bq = d_in[10];
  const void* rwb = d_in[11];
  const void* rrb = d_in[12];
  const void* spanv = d_in[13];

  char* ws = (char*)d_ws;
  size_t off = 0;
  auto alloc = [&](size_t bytes) -> char* {
    char* p = ws + off;
    off += (bytes + 255) & ~(size_t)255;
    return p;
  };
  int* flag = (int*)alloc(256);
  const size_t SZ_W = (size_t)HID_ * HID_ * 2;
  __hip_bfloat16* wqT = (__hip_bfloat16*)alloc(SZ_W);
  __hip_bfloat16* wkT = (__hip_bfloat16*)alloc(SZ_W);   // contiguous with wvT (SZ_W is 256B-aligned)
  __hip_bfloat16* wvT = (__hip_bfloat16*)alloc(SZ_W);
  __hip_bfloat16* wrT = (__hip_bfloat16*)alloc(SZ_W);
  __hip_bfloat16* woT = (__hip_bfloat16*)alloc(SZ_W);
  __hip_bfloat16* kvln = (__hip_bfloat16*)alloc((size_t)B_ * KL_ * HID_ * 2);
  __hip_bfloat16* qln  = (__hip_bfloat16*)alloc((size_t)B_ * Q_ * HID_ * 2);
  __hip_bfloat16* pe   = (__hip_bfloat16*)alloc((size_t)KL_ * HID_ * 2);
  __hip_bfloat16* qpw  = (__hip_bfloat16*)alloc((size_t)B_ * Q_ * HID_ * 2);
  __hip_bfloat16* qpr  = (__hip_bfloat16*)alloc((size_t)B_ * Q_ * HID_ * 2);
  __hip_bfloat16* kpb  = (__hip_bfloat16*)alloc((size_t)B_ * KL_ * HID_ * 2);
  __hip_bfloat16* vptb = (__hip_bfloat16*)alloc((size_t)B_ * KL_ * HID_ * 2);  // V, transposed per-head
  __hip_bfloat16* relp = (__hip_bfloat16*)alloc((size_t)KL_ * HID_ * 2);
  __hip_bfloat16* aout = (__hip_bfloat16*)alloc((size_t)B_ * Q_ * HID_ * 2);

  dim3 tb(256);
  detect_kernel<<<dim3(1), tb, 0, stream>>>((const unsigned int*)query, flag);

  wtpe_kernel<<<dim3(16, 16, 21), tb, 0, stream>>>(Wq, Wk, Wv, Wr, Wo,
                                                   wqT, wkT, wvT, wrT, woT, pe, flag);

  ln_kernel<<<dim3(B_ * KL_ + B_ * Q_), tb, 0, stream>>>(memory, query, gmem, bmem, gq, bq,
                                                         kvln, qln, flag);

  gemm_q<<<dim3(B_ * Q_ / 128, HID_ / 128), tb, 0, stream>>>(qln, wqT, rwb, rrb, qpw, qpr, flag);
  gemm_dualv<<<dim3(B_ * KL_ / 128, 2 * HID_ / 128), tb, 0, stream>>>(kvln, wkT, kpb, vptb);
  gemm_bt128<<<dim3(KL_ / 128, HID_ / 128), tb, 0, stream>>>(pe, wrT, relp, 1.0f);

  attn_kernel<<<dim3((Q_ / RT_) * H_ * B_), tb, 0, stream>>>(qpw, qpr, kpb, vptb, relp, spanv, aout, flag);

  gemm_out<<<dim3(B_ * Q_ / 128, HID_ / 128), tb, 0, stream>>>(aout, woT, d_out, flag);

  (void)in_sizes; (void)n_in; (void)out_size; (void)ws_size;
}

// Round 9
// 462.423 us; speedup vs baseline: 1.1116x; 1.0296x over previous
//
#include <hip/hip_runtime.h>
#include <hip/hip_bf16.h>
#include <math.h>

#define B_   2
#define Q_   2048
#define M_   2048
#define H_   16
#define D_   64
#define HID_ 1024
#define KL_  4096
#define RT_  128     // q rows per attention block
#define WT_  64      // k cols per attention tile
#define LSCL 0.022542110013890053f   // log2(e)/64 — logits kept in log2 units

typedef short short8 __attribute__((ext_vector_type(8)));
typedef short short4v __attribute__((ext_vector_type(4)));
typedef float f32x4 __attribute__((ext_vector_type(4)));
typedef float f32x16 __attribute__((ext_vector_type(16)));
typedef unsigned int uint2v __attribute__((ext_vector_type(2)));

__device__ __forceinline__ void async_copy16(const void* g, void* l) {
  __builtin_amdgcn_global_load_lds((const __attribute__((address_space(1))) unsigned int*)g,
                                   (__attribute__((address_space(3))) unsigned int*)l,
                                   16, 0, 0);
}

// read input element i as float, md=1 -> fp32 buffer, md=0 -> bf16 buffer
__device__ __forceinline__ float ldin(const void* p, size_t i, int md) {
  return md ? ((const float*)p)[i] : __bfloat162float(((const __hip_bfloat16*)p)[i]);
}

__device__ __forceinline__ short bfbits(float v) {
  __hip_bfloat16 t = __float2bfloat16(v);
  return *(short*)&t;
}

// fast 2^x: lowers to v_exp_f32 (HW computes 2^x natively)
__device__ __forceinline__ float fexp2(float x) { return exp2f(x); }

// ---------------- dtype detector: writes 1 if inputs are fp32, else 0 ----------------
__global__ __launch_bounds__(256) void detect_kernel(const unsigned int* __restrict__ q,
                                                     int* __restrict__ flag) {
  __shared__ int cnt;
  if (threadIdx.x == 0) cnt = 0;
  __syncthreads();
  int ins = 0;
#pragma unroll
  for (int i = 0; i < 4; i++) {
    unsigned int u = q[threadIdx.x * 4 + i];
    int e0 = (int)((u >> 7) & 0xffu);
    int e1 = (int)((u >> 23) & 0xffu);
    if (e0 == 0xff || e0 < 102 || e0 > 140) ins++;
    if (e1 == 0xff || e1 < 102 || e1 > 140) ins++;
  }
  atomicAdd(&cnt, ins);
  __syncthreads();
  if (threadIdx.x == 0) *flag = (cnt > 512) ? 1 : 0;
}

// ---------------- fused: 5 weight transposes (z<5) + sinusoidal pos-emb (z>=5) ----------------
__global__ __launch_bounds__(256) void wtpe_kernel(
    const void* __restrict__ s0, const void* __restrict__ s1, const void* __restrict__ s2,
    const void* __restrict__ s3, const void* __restrict__ s4,
    __hip_bfloat16* __restrict__ d0, __hip_bfloat16* __restrict__ d1,
    __hip_bfloat16* __restrict__ d2, __hip_bfloat16* __restrict__ d3,
    __hip_bfloat16* __restrict__ d4, __hip_bfloat16* __restrict__ pe,
    const int* __restrict__ mode) {
  const int tid = threadIdx.x;
  if (blockIdx.z >= 5) {
    // pos-emb: positions K-1..0
    const int p = (blockIdx.z - 5) * 256 + blockIdx.y * 16 + blockIdx.x;
    const float pos = (float)(KL_ - 1 - p);
#pragma unroll
    for (int i = 0; i < 4; i++) {
      int c = tid * 4 + i;
      int f = (c < 512) ? c : c - 512;
      float invf = fexp2(-(float)f * (13.287712379549449f / 512.0f));
      float a = pos * invf;
      float v = (c < 512) ? __sinf(a) : __cosf(a);
      pe[(size_t)p * HID_ + c] = __float2bfloat16(v);
    }
    return;
  }
  const int md = *mode;
  const void* src; __hip_bfloat16* dst;
  switch (blockIdx.z) {
    case 0: src = s0; dst = d0; break;
    case 1: src = s1; dst = d1; break;
    case 2: src = s2; dst = d2; break;
    case 3: src = s3; dst = d3; break;
    default: src = s4; dst = d4; break;
  }
  const int r0 = blockIdx.x * 64, c0 = blockIdx.y * 64;
  __shared__ __hip_bfloat16 t[64][65];
  const int col = tid & 63, r4 = tid >> 6;
#pragma unroll
  for (int i = 0; i < 16; i++)
    t[r4 + i * 4][col] = __float2bfloat16(ldin(src, (size_t)(r0 + r4 + i * 4) * HID_ + c0 + col, md));
  __syncthreads();
#pragma unroll
  for (int i = 0; i < 16; i++)
    dst[(size_t)(c0 + r4 + i * 4) * HID_ + r0 + col] = t[col][r4 + i * 4];
}

// ---------------- fused LayerNorm: rows [0,B*KL) = concat(mem,query); rows >= B*KL = query ----------------
__global__ __launch_bounds__(256) void ln_kernel(
    const void* __restrict__ mem, const void* __restrict__ qry,
    const void* __restrict__ gmem, const void* __restrict__ bmem,
    const void* __restrict__ gq, const void* __restrict__ bq,
    __hip_bfloat16* __restrict__ kvout, __hip_bfloat16* __restrict__ qout,
    const int* __restrict__ mode) {
  const int md = *mode;
  const int row = blockIdx.x;  // 0..B*KL + B*Q - 1
  const void* src;
  const void* gamma; const void* beta;
  size_t base;
  __hip_bfloat16* dst;
  if (row < B_ * KL_) {
    const int b = row / KL_, j = row % KL_;
    if (j < M_) { src = mem; base = ((size_t)b * M_ + j) * HID_; }
    else        { src = qry; base = ((size_t)b * Q_ + (j - M_)) * HID_; }
    gamma = gmem; beta = bmem;
    dst = kvout + (size_t)row * HID_;
  } else {
    const int r = row - B_ * KL_;
    src = qry; base = (size_t)r * HID_;
    gamma = gq; beta = bq;
    dst = qout + (size_t)r * HID_;
  }
  const int tid = threadIdx.x;
  float x[4];
  float s = 0.f, ss = 0.f;
#pragma unroll
  for (int i = 0; i < 4; i++) {
    x[i] = ldin(src, base + i * 256 + tid, md);
    s += x[i]; ss += x[i] * x[i];
  }
#pragma unroll
  for (int o = 32; o > 0; o >>= 1) { s += __shfl_down(s, o); ss += __shfl_down(ss, o); }
  __shared__ float red[8];
  if ((tid & 63) == 0) { red[(tid >> 6) * 2] = s; red[(tid >> 6) * 2 + 1] = ss; }
  __syncthreads();
  float ts = 0.f, tss = 0.f;
#pragma unroll
  for (int i = 0; i < 4; i++) { ts += red[i * 2]; tss += red[i * 2 + 1]; }
  const float mu = ts * (1.f / 1024.f);
  const float var = tss * (1.f / 1024.f) - mu * mu;
  const float rs = rsqrtf(var + 1e-3f);
#pragma unroll
  for (int i = 0; i < 4; i++) {
    int c = i * 256 + tid;
    dst[c] = __float2bfloat16((x[i] - mu) * rs * ldin(gamma, c, md) + ldin(beta, c, md));
  }
}

// ---------------- GEMM core: C = A @ BT^T (both bf16, K=1024), 128x128 tile, BK=64 ----------------
template <int WRITE_MODE_SWITCH>
__device__ __forceinline__ void gemm_body(const __hip_bfloat16* __restrict__ A,
                                          const __hip_bfloat16* __restrict__ BT,
                                          void* __restrict__ C, int md, float scl) {
  __shared__ __attribute__((aligned(16))) __hip_bfloat16 sA[128 * 64];
  __shared__ __attribute__((aligned(16))) __hip_bfloat16 sB[128 * 64];
  const int tid = threadIdx.x;
  const int lane = tid & 63;
  const int w = tid >> 6;
  const int quad = lane >> 4, l16 = lane & 15;
  const int m0 = blockIdx.x * 128;
  const int n0 = blockIdx.y * 128;
  const int wm = (w >> 1) * 64, wn = (w & 1) * 64;
  const f32x4 fz = {0.f, 0.f, 0.f, 0.f};

  f32x4 acc[4][4];
#pragma unroll
  for (int i = 0; i < 4; i++)
#pragma unroll
    for (int j = 0; j < 4; j++) acc[i][j] = fz;

  for (int kk = 0; kk < HID_ / 64; kk++) {
    const int k0 = kk * 64;
    __syncthreads();
#pragma unroll
    for (int t = 0; t < 4; t++) {
      int c = (w * 4 + t) * 64 + lane;
      int row = c >> 3;
      int cid = (c & 7) ^ (row & 7);
      async_copy16(A + (size_t)(m0 + row) * HID_ + k0 + cid * 8, (char*)sA + c * 16);
      async_copy16(BT + (size_t)(n0 + row) * HID_ + k0 + cid * 8, (char*)sB + c * 16);
    }
    __syncthreads();
#pragma unroll
    for (int half = 0; half < 2; half++) {
      short8 af[4], bf[4];
#pragma unroll
      for (int mt = 0; mt < 4; mt++) {
        int r = wm + mt * 16 + l16;
        af[mt] = *(const short8*)((const char*)sA + r * 128 + (((half * 4 + quad) ^ (r & 7)) * 16));
      }
#pragma unroll
      for (int nt = 0; nt < 4; nt++) {
        int r = wn + nt * 16 + l16;
        bf[nt] = *(const short8*)((const char*)sB + r * 128 + (((half * 4 + quad) ^ (r & 7)) * 16));
      }
#pragma unroll
      for (int mt = 0; mt < 4; mt++)
#pragma unroll
        for (int nt = 0; nt < 4; nt++)
          acc[mt][nt] = __builtin_amdgcn_mfma_f32_16x16x32_bf16(af[mt], bf[nt], acc[mt][nt], 0, 0, 0);
    }
  }
#pragma unroll
  for (int mt = 0; mt < 4; mt++)
#pragma unroll
    for (int nt = 0; nt < 4; nt++)
#pragma unroll
      for (int rg = 0; rg < 4; rg++) {
        int r = m0 + wm + mt * 16 + quad * 4 + rg;
        int cc = n0 + wn + nt * 16 + l16;
        size_t idx = (size_t)r * HID_ + cc;
        if (WRITE_MODE_SWITCH && md) ((float*)C)[idx] = acc[mt][nt][rg];
        else ((__hip_bfloat16*)C)[idx] = __float2bfloat16(acc[mt][nt][rg] * scl);
      }
}

__global__ __launch_bounds__(256) void gemm_bt128(const __hip_bfloat16* __restrict__ A,
                                                  const __hip_bfloat16* __restrict__ BT,
                                                  __hip_bfloat16* __restrict__ C, float scl) {
  gemm_body<0>(A, BT, (void*)C, 0, scl);
}

__global__ __launch_bounds__(256) void gemm_out(const __hip_bfloat16* __restrict__ A,
                                                const __hip_bfloat16* __restrict__ BT,
                                                void* __restrict__ C,
                                                const int* __restrict__ mode) {
  gemm_body<1>(A, BT, C, *mode, 1.0f);
}

// ---- q-projection GEMM with dual-bias epilogue: qw=(acc+rwb)*LSCL, qr=(acc+rrb)*LSCL (BK=64) ----
__global__ __launch_bounds__(256) void gemm_q(const __hip_bfloat16* __restrict__ A,
                                              const __hip_bfloat16* __restrict__ BT,
                                              const void* __restrict__ rwb,
                                              const void* __restrict__ rrb,
                                              __hip_bfloat16* __restrict__ qw,
                                              __hip_bfloat16* __restrict__ qr,
                                              const int* __restrict__ mode) {
  const int md = *mode;
  __shared__ __attribute__((aligned(16))) __hip_bfloat16 sA[128 * 64];
  __shared__ __attribute__((aligned(16))) __hip_bfloat16 sB[128 * 64];
  const int tid = threadIdx.x;
  const int lane = tid & 63;
  const int w = tid >> 6;
  const int quad = lane >> 4, l16 = lane & 15;
  const int m0 = blockIdx.x * 128;
  const int n0 = blockIdx.y * 128;
  const int wm = (w >> 1) * 64, wn = (w & 1) * 64;
  const f32x4 fz = {0.f, 0.f, 0.f, 0.f};

  f32x4 acc[4][4];
#pragma unroll
  for (int i = 0; i < 4; i++)
#pragma unroll
    for (int j = 0; j < 4; j++) acc[i][j] = fz;

  for (int kk = 0; kk < HID_ / 64; kk++) {
    const int k0 = kk * 64;
    __syncthreads();
#pragma unroll
    for (int t = 0; t < 4; t++) {
      int c = (w * 4 + t) * 64 + lane;
      int row = c >> 3;
      int cid = (c & 7) ^ (row & 7);
      async_copy16(A + (size_t)(m0 + row) * HID_ + k0 + cid * 8, (char*)sA + c * 16);
      async_copy16(BT + (size_t)(n0 + row) * HID_ + k0 + cid * 8, (char*)sB + c * 16);
    }
    __syncthreads();
#pragma unroll
    for (int half = 0; half < 2; half++) {
      short8 af[4], bf[4];
#pragma unroll
      for (int mt = 0; mt < 4; mt++) {
        int r = wm + mt * 16 + l16;
        af[mt] = *(const short8*)((const char*)sA + r * 128 + (((half * 4 + quad) ^ (r & 7)) * 16));
      }
#pragma unroll
      for (int nt = 0; nt < 4; nt++) {
        int r = wn + nt * 16 + l16;
        bf[nt] = *(const short8*)((const char*)sB + r * 128 + (((half * 4 + quad) ^ (r & 7)) * 16));
      }
#pragma unroll
      for (int mt = 0; mt < 4; mt++)
#pragma unroll
        for (int nt = 0; nt < 4; nt++)
          acc[mt][nt] = __builtin_amdgcn_mfma_f32_16x16x32_bf16(af[mt], bf[nt], acc[mt][nt], 0, 0, 0);
    }
  }
  float bw[4], br[4];
#pragma unroll
  for (int nt = 0; nt < 4; nt++) {
    int cc = n0 + wn + nt * 16 + l16;
    bw[nt] = ldin(rwb, cc, md);
    br[nt] = ldin(rrb, cc, md);
  }
#pragma unroll
  for (int mt = 0; mt < 4; mt++)
#pragma unroll
    for (int nt = 0; nt < 4; nt++)
#pragma unroll
      for (int rg = 0; rg < 4; rg++) {
        int r = m0 + wm + mt * 16 + quad * 4 + rg;
        int cc = n0 + wn + nt * 16 + l16;
        size_t idx = (size_t)r * HID_ + cc;
        float a = acc[mt][nt][rg];
        qw[idx] = __float2bfloat16((a + bw[nt]) * LSCL);
        qr[idx] = __float2bfloat16((a + br[nt]) * LSCL);
      }
}

// ---- dual GEMM: BT = contiguous [wkT; wvT]; K-half -> kpb (row-major), V-half -> vpt
// (transposed per-head layout [b][h][d][j]). BK=64; transpose scratch sT unioned with
// sA/sB (epilogue-only use, barrier-guarded) -> 34.8 KB LDS total. ----
__global__ __launch_bounds__(256) void gemm_dualv(const __hip_bfloat16* __restrict__ A,
                                                  const __hip_bfloat16* __restrict__ BT,
                                                  __hip_bfloat16* __restrict__ C0,
                                                  __hip_bfloat16* __restrict__ vpt) {
  __shared__ __attribute__((aligned(16))) char smem[128 * 136 * 2];  // 34816 B >= sA+sB (32768)
  __hip_bfloat16* sA = (__hip_bfloat16*)smem;
  __hip_bfloat16* sB = (__hip_bfloat16*)(smem + 16384);
  short* sT = (short*)smem;
  const int tid = threadIdx.x;
  const int lane = tid & 63;
  const int w = tid >> 6;
  const int quad = lane >> 4, l16 = lane & 15;
  const int m0 = blockIdx.x * 128;
  const int n0 = blockIdx.y * 128;  // 0..1920
  const int wm = (w >> 1) * 64, wn = (w & 1) * 64;
  const f32x4 fz = {0.f, 0.f, 0.f, 0.f};

  f32x4 acc[4][4];
#pragma unroll
  for (int i = 0; i < 4; i++)
#pragma unroll
    for (int j = 0; j < 4; j++) acc[i][j] = fz;

  for (int kk = 0; kk < HID_ / 64; kk++) {
    const int k0 = kk * 64;
    __syncthreads();
#pragma unroll
    for (int t = 0; t < 4; t++) {
      int c = (w * 4 + t) * 64 + lane;
      int row = c >> 3;
      int cid = (c & 7) ^ (row & 7);
      async_copy16(A + (size_t)(m0 + row) * HID_ + k0 + cid * 8, (char*)sA + c * 16);
      async_copy16(BT + (size_t)(n0 + row) * HID_ + k0 + cid * 8, (char*)sB + c * 16);
    }
    __syncthreads();
#pragma unroll
    for (int half = 0; half < 2; half++) {
      short8 af[4], bf[4];
#pragma unroll
      for (int mt = 0; mt < 4; mt++) {
        int r = wm + mt * 16 + l16;
        af[mt] = *(const short8*)((const char*)sA + r * 128 + (((half * 4 + quad) ^ (r & 7)) * 16));
      }
#pragma unroll
      for (int nt = 0; nt < 4; nt++) {
        int r = wn + nt * 16 + l16;
        bf[nt] = *(const short8*)((const char*)sB + r * 128 + (((half * 4 + quad) ^ (r & 7)) * 16));
      }
#pragma unroll
      for (int mt = 0; mt < 4; mt++)
#pragma unroll
        for (int nt = 0; nt < 4; nt++)
          acc[mt][nt] = __builtin_amdgcn_mfma_f32_16x16x32_bf16(af[mt], bf[nt], acc[mt][nt], 0, 0, 0);
    }
  }
  if (n0 < HID_) {
    // K half: row-major write
#pragma unroll
    for (int mt = 0; mt < 4; mt++)
#pragma unroll
      for (int nt = 0; nt < 4; nt++)
#pragma unroll
        for (int rg = 0; rg < 4; rg++) {
          int r = m0 + wm + mt * 16 + quad * 4 + rg;
          int cc = n0 + wn + nt * 16 + l16;
          C0[(size_t)r * HID_ + cc] = __float2bfloat16(acc[mt][nt][rg]);
        }
  } else {
    // V half: transpose through sT (unioned with sA/sB) -> vpt[((b*H+h)*D+d)*KL + j]
    __syncthreads();  // all MFMA LDS reads done before sT overwrites sA/sB space
#pragma unroll
    for (int mt = 0; mt < 4; mt++)
#pragma unroll
      for (int nt = 0; nt < 4; nt++) {
        int r = wm + mt * 16 + quad * 4;   // local j base (rg 0..3 consecutive)
        int cc = wn + nt * 16 + l16;       // local col
        short4v pk;
#pragma unroll
        for (int rg = 0; rg < 4; rg++) pk[rg] = bfbits(acc[mt][nt][rg]);
        *(short4v*)&sT[cc * 136 + r] = pk;
      }
    __syncthreads();
    const int b = m0 >> 12;            // 4096 rows per batch
    const int j0g = m0 & (KL_ - 1);
    const int cg0 = n0 - HID_;
#pragma unroll
    for (int it = 0; it < 16; it++) {
      int cc = it * 8 + w * 2 + (lane >> 5);
      int jj = (lane & 31) * 4;
      int cg = cg0 + cc;
      int h = cg >> 6, d = cg & 63;
      short4v v = *(const short4v*)&sT[cc * 136 + jj];
      *(short4v*)(vpt + (((size_t)(b * H_ + h)) * D_ + d) * KL_ + j0g + jj) = v;
    }
  }
}

// ---------------- fused relative attention, 32x32 MFMA, SPLIT-K halves ----------------
// grid 1024 = 32 bh x 16 rk x 2 halves, longest-first (rk descending). Each half runs
// (17+rk) tiles of the round-8 inner loop and writes UNNORMALIZED partials:
// opart[half] (f32 O-accum) + mlbuf[half] (m, l, df per q-row). merge_kernel combines.
// Max block length 32 tiles (vs 64 fused) -> per-CU makespan ~49 tile-units (vs 64).
__global__ __launch_bounds__(256, 2) void attn_kernel(
    const __hip_bfloat16* __restrict__ qpw, const __hip_bfloat16* __restrict__ qpr,
    const __hip_bfloat16* __restrict__ kp, const __hip_bfloat16* __restrict__ vpt,
    const __hip_bfloat16* __restrict__ relp,
    const void* __restrict__ spanv,
    float* __restrict__ opart, float* __restrict__ mlbuf,
    const int* __restrict__ mode) {
  const int md = *mode;
  const int bid = blockIdx.x;          // 0..1023
  const int g = bid >> 1, half = bid & 1;
  const int rk = 15 - (g >> 5);        // longest (rk=15) dispatched first
  const int bh = g & 31;
  const int i0 = rk << 7;
  const int b = bh >> 4, h = bh & 15;
  const int nt = 34 + 2 * rk;          // total tiles for this (i0); always even
  const int nt2 = nt >> 1;
  const int kt0 = half ? nt2 : 0;
  const int kt1 = half ? nt : nt2;

  const int tid = threadIdx.x;
  const int lane = tid & 63;
  const int w = tid >> 6;
  const int l31 = lane & 31, hi = lane >> 5;
  const int di = w * 32 + l31;          // this thread's softmax row (block-local)
  const int iRow = i0 + di;

  __shared__ __attribute__((aligned(16))) __hip_bfloat16 sk[64 * 64];     // 8 KB K tile
  __shared__ __attribute__((aligned(16))) __hip_bfloat16 srel[192 * 64];  // 24 KB circular rel band
  __shared__ __attribute__((aligned(16))) __hip_bfloat16 svt[64 * 64];    // 8 KB V^T tile
  __shared__ __attribute__((aligned(16))) short sTP[128 * 100];           // 25 KB T rows, stride 200 B

  const int rb = di * 200;              // private row base (bytes), 8B-aligned
  const int sw = l31 & 7;               // swizzle key (== row&7 for all operand reads)

  const __hip_bfloat16* kbase = kp + (size_t)b * KL_ * HID_ + h * D_;
  const __hip_bfloat16* vtb = vpt + ((size_t)(b * H_ + h)) * D_ * KL_;
  const float sv = ldin(spanv, h, md);
  const float svQ = sv * (float)Q_;
  const int pb0 = Q_ - RT_ - i0;
  const int wof = (3 - w) * 32;         // this wave's T-band p-window offset
  const int jb0 = kt0 * WT_;            // this half's starting column

  const f32x16 z16 = {0.f,0.f,0.f,0.f,0.f,0.f,0.f,0.f,0.f,0.f,0.f,0.f,0.f,0.f,0.f,0.f};

  // ---- q' / q'' fragments: direct global loads of own row (one-time) ----
  short8 qf[4], qrf[4];
  {
    const size_t qofs = ((size_t)(b * Q_ + iRow)) * HID_ + h * D_;
#pragma unroll
    for (int ks = 0; ks < 4; ks++) {
      qf[ks]  = *(const short8*)(qpw + qofs + ks * 16 + hi * 8);
      qrf[ks] = *(const short8*)(qpr + qofs + ks * 16 + hi * 8);
    }
  }

  // ---- first tile staged via DMA (K, full 192-row rel band, V^T) at column jb0 ----
  {
#pragma unroll
    for (int t = 0; t < 2; t++) {
      int c = (w * 2 + t) * 64 + lane;
      int row = c >> 3;
      int cid = (c & 7) ^ (row & 7);
      async_copy16(kbase + (size_t)(jb0 + row) * HID_ + cid * 8, (char*)sk + c * 16);
      async_copy16(vtb + (size_t)row * KL_ + jb0 + cid * 8, (char*)svt + c * 16);
    }
#pragma unroll
    for (int t = 0; t < 6; t++) {
      int c = (w * 6 + t) * 64 + lane;
      int row = c >> 3;                  // 0..191
      int cid = (c & 7) ^ (row & 7);
      int p = pb0 + jb0 + row; p = p < KL_ ? p : KL_ - 1;
      async_copy16(relp + (size_t)p * HID_ + h * D_ + cid * 8, (char*)srel + c * 16);
    }
  }

  float mrow = -3e38f, lrow = 0.f, dfrow = 0.f;
  f32x16 oacc[2];
  oacc[0] = z16; oacc[1] = z16;
  int rot = 0;                          // local circular rotation, (iter % 3) * 64

  for (int kt = kt0; kt < kt1; kt++) {
    const int j0 = kt * WT_;

    __syncthreads();  // B: tile kt staging (DMA or ds_writes) visible

    // ---- prefetch tile kt+1 into registers (issued before compute; committed after) ----
    short8 rK[2], rR[2], rV[2];
    const bool pf = (kt + 1 < kt1);
    {
      int j0n = j0 + WT_; if (j0n > KL_ - WT_) j0n = KL_ - WT_;
#pragma unroll
      for (int t = 0; t < 2; t++) {
        int c = (w * 2 + t) * 64 + lane;
        int row = c >> 3;
        int cid = (c & 7) ^ (row & 7);
        rK[t] = *(const short8*)(kbase + (size_t)(j0n + row) * HID_ + cid * 8);
        rV[t] = *(const short8*)(vtb + (size_t)row * KL_ + j0n + cid * 8);
        int p = pb0 + (kt + 1) * 64 + 128 + row; p = p < KL_ ? p : KL_ - 1;
        rR[t] = *(const short8*)(relp + (size_t)p * HID_ + h * D_ + cid * 8);
      }
    }
    __builtin_amdgcn_sched_barrier(0);  // pin load issue above the compute phase

    // ---- S^T[j][i] = K . q'^T ----
    __builtin_amdgcn_s_setprio(1);
    f32x16 S[2];
    S[0] = z16; S[1] = z16;
#pragma unroll
    for (int mt = 0; mt < 2; mt++) {
      const char* rowp = (const char*)sk + (mt * 32 + l31) * 128;
#pragma unroll
      for (int ks = 0; ks < 4; ks++) {
        short8 af = *(const short8*)(rowp + (((ks * 2 + hi) ^ sw) * 16));
        S[mt] = __builtin_amdgcn_mfma_f32_32x32x16_bf16(af, qf[ks], S[mt], 0, 0, 0);
      }
    }

    // ---- T band (wave's 96-row p-window) = rel . q''^T, store into own sTP row ----
#pragma unroll
    for (int mt = 0; mt < 3; mt++) {
      f32x16 T = z16;
      int rr = wof + mt * 32 + l31 + rot; if (rr >= 192) rr -= 192;
      const char* rowp = (const char*)srel + rr * 128;
#pragma unroll
      for (int ks = 0; ks < 4; ks++) {
        short8 af = *(const short8*)(rowp + (((ks * 2 + hi) ^ sw) * 16));
        T = __builtin_amdgcn_mfma_f32_32x32x16_bf16(af, qrf[ks], T, 0, 0, 0);
      }
#pragma unroll
      for (int r2 = 0; r2 < 4; r2++) {
        short4v pk;
#pragma unroll
        for (int r4 = 0; r4 < 4; r4++) pk[r4] = bfbits(T[r2 * 4 + r4]);
        *(short4v*)((char*)sTP + rb + (mt * 32 + 8 * r2 + 4 * hi) * 2) = pk;
      }
    }
    __builtin_amdgcn_s_setprio(0);

    // ---- gather with per-row shift (own row, in-order DS) ----
    {
      const char* tb2 = (const char*)sTP + rb + (31 - l31 + 4 * hi) * 2;
#pragma unroll
      for (int mt = 0; mt < 2; mt++)
#pragma unroll
        for (int r2 = 0; r2 < 4; r2++)
#pragma unroll
          for (int r4 = 0; r4 < 4; r4++)
            S[mt][r2 * 4 + r4] +=
                __bfloat162float(*(const __hip_bfloat16*)(tb2 + (mt * 32 + 8 * r2 + r4) * 2));
    }

    // ---- logits (log2 units), causal mask only on tiles that can need it ----
    const bool causalT = (j0 + WT_ - 1 - i0) > M_;
    if (causalT) {
#pragma unroll
      for (int mt = 0; mt < 2; mt++)
#pragma unroll
        for (int r2 = 0; r2 < 4; r2++)
#pragma unroll
          for (int r4 = 0; r4 < 4; r4++) {
            int j = j0 + mt * 32 + 8 * r2 + 4 * hi + r4;
            if (j - iRow > M_) S[mt][r2 * 4 + r4] = -1e30f;
          }
    }
    // tree max: depth ~6 instead of 32-deep serial chain (clang fuses to v_max3)
    float m8[8];
#pragma unroll
    for (int g2 = 0; g2 < 8; g2++) {
      int mt = g2 >> 2, r2 = g2 & 3;
      m8[g2] = fmaxf(fmaxf(S[mt][r2 * 4 + 0], S[mt][r2 * 4 + 1]),
                     fmaxf(S[mt][r2 * 4 + 2], S[mt][r2 * 4 + 3]));
    }
    float mnew = fmaxf(mrow,
        fmaxf(fmaxf(fmaxf(m8[0], m8[1]), fmaxf(m8[2], m8[3])),
              fmaxf(fmaxf(m8[4], m8[5]), fmaxf(m8[6], m8[7]))));
    mnew = fmaxf(mnew, __shfl_xor(mnew, 32));
    // T13 defer-max: skip rescale while tile max growth <= 8 (P bounded by 2^8)
    if (!__all(mnew - mrow <= 8.f)) {
      const float alpha = fexp2(mrow - mnew);
      mrow = mnew;
      lrow *= alpha; dfrow *= alpha;
#pragma unroll
      for (int dt = 0; dt < 2; dt++)
#pragma unroll
        for (int rg = 0; rg < 16; rg++) oacc[dt][rg] *= alpha;
    }

    // ---- P = exp2(S-m) in-register; span deficit on ramp tiles; permlane assembly ----
    const bool maskT = (j0 + WT_ > M_) && ((float)j0 < (float)M_ + 33.f - svQ);
    short8 paf[4];
#pragma unroll
    for (int mt = 0; mt < 2; mt++) {
      unsigned Pp[4][2];
#pragma unroll
      for (int r2 = 0; r2 < 4; r2++) {
        short4v g3;
        float pvv[4];
#pragma unroll
        for (int r4 = 0; r4 < 4; r4++) {
          float pv = fexp2(S[mt][r2 * 4 + r4] - mrow);
          pvv[r4] = pv;
          float pm = pv;
          if (maskT) {
            int j = j0 + mt * 32 + 8 * r2 + 4 * hi + r4;
            if (j >= M_) {
              float t0 = (float)(j - M_) + svQ;
              float mk = fminf(fmaxf(t0 * (1.0f / 33.0f), 0.f), 1.f);
              pm = pv * mk;
              dfrow += pv - pm;
            }
          }
          g3[r4] = bfbits(pm);
        }
        lrow += (pvv[0] + pvv[1]) + (pvv[2] + pvv[3]);  // tree partial, short dep chain
        union { short4v s; unsigned u[2]; } cv; cv.s = g3;
        Pp[r2][0] = cv.u[0]; Pp[r2][1] = cv.u[1];
      }
#pragma unroll
      for (int hf = 0; hf < 2; hf++) {
        uint2v rA = __builtin_amdgcn_permlane32_swap(Pp[hf * 2][0], Pp[hf * 2 + 1][0], false, false);
        uint2v rB = __builtin_amdgcn_permlane32_swap(Pp[hf * 2][1], Pp[hf * 2 + 1][1], false, false);
        union { unsigned u[4]; short8 s; } asm8;
        asm8.u[0] = rA[0]; asm8.u[1] = rB[0]; asm8.u[2] = rA[1]; asm8.u[3] = rB[1];
        paf[mt * 2 + hf] = asm8.s;
      }
    }

    // ---- PV (swapped): A = V^T rows (M=d), B = P (N = own q-row) ----
    __builtin_amdgcn_s_setprio(1);
#pragma unroll
    for (int dt = 0; dt < 2; dt++) {
      const char* rowp = (const char*)svt + (dt * 32 + l31) * 128;
#pragma unroll
      for (int ks = 0; ks < 4; ks++) {
        short8 bfv = *(const short8*)(rowp + (((ks * 2 + hi) ^ sw) * 16));
        oacc[dt] = __builtin_amdgcn_mfma_f32_32x32x16_bf16(bfv, paf[ks], oacc[dt], 0, 0, 0);
      }
    }
    __builtin_amdgcn_s_setprio(0);

    __syncthreads();  // A: all LDS consumers of tile kt done

    // ---- commit prefetched tile kt+1 to LDS (vmcnt drain here, after compute) ----
    if (pf) {
#pragma unroll
      for (int t = 0; t < 2; t++) {
        int c = (w * 2 + t) * 64 + lane;
        int row = c >> 3;
        *(short8*)((char*)sk + c * 16) = rK[t];
        *(short8*)((char*)svt + c * 16) = rV[t];
        *(short8*)((char*)srel + (rot + row) * 128 + (c & 7) * 16) = rR[t];
      }
    }
    rot += 64; if (rot == 192) rot = 0;
  }

  // ---- epilogue: write unnormalized partials (f32 O + per-row m/l/df) ----
  lrow += __shfl_xor(lrow, 32);
  dfrow += __shfl_xor(dfrow, 32);
  float* ob = opart + (size_t)half * B_ * Q_ * HID_ + ((size_t)(b * Q_ + iRow)) * HID_ + h * D_;
#pragma unroll
  for (int dt = 0; dt < 2; dt++)
#pragma unroll
    for (int r2 = 0; r2 < 4; r2++) {
      f32x4 o = {oacc[dt][r2 * 4 + 0], oacc[dt][r2 * 4 + 1],
                 oacc[dt][r2 * 4 + 2], oacc[dt][r2 * 4 + 3]};
      *(f32x4*)(ob + dt * 32 + 8 * r2 + 4 * hi) = o;
    }
  if (hi == 0) {
    f32x4 mlv = {mrow, lrow, dfrow, 0.f};
    *(f32x4*)(mlbuf + ((size_t)half * B_ * H_ * Q_ + ((size_t)(b * H_ + h)) * Q_ + iRow) * 4) = mlv;
  }
}

// ---------------- split-K merge: aout = (o0*a0 + o1*a1) / denom ----------------
__global__ __launch_bounds__(256) void merge_kernel(
    const float* __restrict__ opart, const float* __restrict__ mlbuf,
    __hip_bfloat16* __restrict__ aout) {
  const int bq = blockIdx.x;              // 0..B*Q-1
  const int b = bq >> 11, q = bq & 2047;
  const int t = threadIdx.x;
  const int h = t >> 4, dg = (t & 15) * 4;
  const size_t mlidx = (((size_t)(b * H_ + h)) * Q_ + q) * 4;
  const size_t MLH = (size_t)B_ * H_ * Q_ * 4;
  f32x4 ml0 = *(const f32x4*)(mlbuf + mlidx);
  f32x4 ml1 = *(const f32x4*)(mlbuf + MLH + mlidx);
  const float ms = fmaxf(ml0[0], ml1[0]);
  const float a0 = fexp2(ml0[0] - ms), a1 = fexp2(ml1[0] - ms);
  const float l = ml0[1] * a0 + ml1[1] * a1;
  const float df = ml0[2] * a0 + ml1[2] * a1;
  const float r = 1.f / ((l - df) + 1e-8f * l);
  const size_t oidx = (size_t)bq * HID_ + h * D_ + dg;
  const size_t OH = (size_t)B_ * Q_ * HID_;
  f32x4 o0 = *(const f32x4*)(opart + oidx);
  f32x4 o1 = *(const f32x4*)(opart + OH + oidx);
  short4v o;
#pragma unroll
  for (int r4 = 0; r4 < 4; r4++) o[r4] = bfbits((o0[r4] * a0 + o1[r4] * a1) * r);
  *(short4v*)(aout + oidx) = o;
}

// ---------------- launcher ----------------
extern "C" void kernel_launch(void* const* d_in, const int* in_sizes, int n_in,
                              void* d_out, int out_size, void* d_ws, size_t ws_size,
                              hipStream_t stream) {
  const void* query  = d_in[0];
  const void* memory = d_in[1];
  const void* Wq = d_in[2];
  const void* Wk = d_in[3];
  const void* Wv = d_in[4];
  const void* Wo = d_in[5];
  const void* Wr = d_in[6];
  const void* gmem = d_in[7];
  const void* bmem = d_in[8];
  const void* gq = d_in[9];
  const void* bq = d_in[10];
  const void* rwb = d_in[11];
  const void* rrb = d_in[12];
  const void* spanv = d_in[13];

  char* ws = (char*)d_ws;
  size_t off = 0;
  auto alloc = [&](size_t bytes) -> char* {
    char* p = ws + off;
    off += (bytes + 255) & ~(size_t)255;
    return p;
  };
  int* flag = (int*)alloc(256);
  const size_t SZ_W = (size_t)HID_ * HID_ * 2;
  __hip_bfloat16* wqT = (__hip_bfloat16*)alloc(SZ_W);
  __hip_bfloat16* wkT = (__hip_bfloat16*)alloc(SZ_W);   // contiguous with wvT (SZ_W is 256B-aligned)
  __hip_bfloat16* wvT = (__hip_bfloat16*)alloc(SZ_W);
  __hip_bfloat16* wrT = (__hip_bfloat16*)alloc(SZ_W);
  __hip_bfloat16* woT = (__hip_bfloat16*)alloc(SZ_W);
  // kvln + qln + pe are dead after the projection GEMMs; their contiguous 33.55 MB
  // is reused as the f32 split-K partial buffer (exactly 2 * B*Q*HID * 4 bytes).
  __hip_bfloat16* kvln = (__hip_bfloat16*)alloc((size_t)B_ * KL_ * HID_ * 2);
  __hip_bfloat16* qln  = (__hip_bfloat16*)alloc((size_t)B_ * Q_ * HID_ * 2);
  __hip_bfloat16* pe   = (__hip_bfloat16*)alloc((size_t)KL_ * HID_ * 2);
  __hip_bfloat16* qpw  = (__hip_bfloat16*)alloc((size_t)B_ * Q_ * HID_ * 2);
  __hip_bfloat16* qpr  = (__hip_bfloat16*)alloc((size_t)B_ * Q_ * HID_ * 2);
  __hip_bfloat16* kpb  = (__hip_bfloat16*)alloc((size_t)B_ * KL_ * HID_ * 2);
  __hip_bfloat16* vptb = (__hip_bfloat16*)alloc((size_t)B_ * KL_ * HID_ * 2);  // V, transposed per-head
  __hip_bfloat16* relp = (__hip_bfloat16*)alloc((size_t)KL_ * HID_ * 2);
  __hip_bfloat16* aout = (__hip_bfloat16*)alloc((size_t)B_ * Q_ * HID_ * 2);
  float* mlbuf = (float*)alloc((size_t)2 * B_ * H_ * Q_ * 4 * sizeof(float));
  float* opart = (float*)kvln;   // 33.55 MB f32 partials overlay (kvln+qln+pe)

  dim3 tb(256);
  detect_kernel<<<dim3(1), tb, 0, stream>>>((const unsigned int*)query, flag);

  wtpe_kernel<<<dim3(16, 16, 21), tb, 0, stream>>>(Wq, Wk, Wv, Wr, Wo,
                                                   wqT, wkT, wvT, wrT, woT, pe, flag);

  ln_kernel<<<dim3(B_ * KL_ + B_ * Q_), tb, 0, stream>>>(memory, query, gmem, bmem, gq, bq,
                                                         kvln, qln, flag);

  gemm_q<<<dim3(B_ * Q_ / 128, HID_ / 128), tb, 0, stream>>>(qln, wqT, rwb, rrb, qpw, qpr, flag);
  gemm_dualv<<<dim3(B_ * KL_ / 128, 2 * HID_ / 128), tb, 0, stream>>>(kvln, wkT, kpb, vptb);
  gemm_bt128<<<dim3(KL_ / 128, HID_ / 128), tb, 0, stream>>>(pe, wrT, relp, 1.0f);

  attn_kernel<<<dim3(1024), tb, 0, stream>>>(qpw, qpr, kpb, vptb, relp, spanv,
                                             opart, mlbuf, flag);
  merge_kernel<<<dim3(B_ * Q_), tb, 0, stream>>>(opart, mlbuf, aout);

  gemm_out<<<dim3(B_ * Q_ / 128, HID_ / 128), tb, 0, stream>>>(aout, woT, d_out, flag);

  (void)in_sizes; (void)n_in; (void)out_size; (void)ws_size;
}

// Round 10
// 433.241 us; speedup vs baseline: 1.1865x; 1.0674x over previous
//
#include <hip/hip_runtime.h>
#include <hip/hip_bf16.h>
#include <math.h>

#define B_   2
#define Q_   2048
#define M_   2048
#define H_   16
#define D_   64
#define HID_ 1024
#define KL_  4096
#define RT_  128     // q rows per attention block
#define WT_  64      // k cols per attention tile
#define LSCL 0.022542110013890053f   // log2(e)/64 — logits kept in log2 units

typedef short short8 __attribute__((ext_vector_type(8)));
typedef short short4v __attribute__((ext_vector_type(4)));
typedef float f32x4 __attribute__((ext_vector_type(4)));
typedef float f32x16 __attribute__((ext_vector_type(16)));
typedef unsigned int uint2v __attribute__((ext_vector_type(2)));

__device__ __forceinline__ void async_copy16(const void* g, void* l) {
  __builtin_amdgcn_global_load_lds((const __attribute__((address_space(1))) unsigned int*)g,
                                   (__attribute__((address_space(3))) unsigned int*)l,
                                   16, 0, 0);
}

// read input element i as float, md=1 -> fp32 buffer, md=0 -> bf16 buffer
__device__ __forceinline__ float ldin(const void* p, size_t i, int md) {
  return md ? ((const float*)p)[i] : __bfloat162float(((const __hip_bfloat16*)p)[i]);
}

__device__ __forceinline__ short bfbits(float v) {
  __hip_bfloat16 t = __float2bfloat16(v);
  return *(short*)&t;
}

// fast 2^x: lowers to v_exp_f32 (HW computes 2^x natively)
__device__ __forceinline__ float fexp2(float x) { return exp2f(x); }

// ---------------- dtype detector: writes 1 if inputs are fp32, else 0 ----------------
__global__ __launch_bounds__(256) void detect_kernel(const unsigned int* __restrict__ q,
                                                     int* __restrict__ flag) {
  __shared__ int cnt;
  if (threadIdx.x == 0) cnt = 0;
  __syncthreads();
  int ins = 0;
#pragma unroll
  for (int i = 0; i < 4; i++) {
    unsigned int u = q[threadIdx.x * 4 + i];
    int e0 = (int)((u >> 7) & 0xffu);
    int e1 = (int)((u >> 23) & 0xffu);
    if (e0 == 0xff || e0 < 102 || e0 > 140) ins++;
    if (e1 == 0xff || e1 < 102 || e1 > 140) ins++;
  }
  atomicAdd(&cnt, ins);
  __syncthreads();
  if (threadIdx.x == 0) *flag = (cnt > 512) ? 1 : 0;
}

// ---------------- fused: 5 weight transposes (z<5) + sinusoidal pos-emb (z>=5) ----------------
__global__ __launch_bounds__(256) void wtpe_kernel(
    const void* __restrict__ s0, const void* __restrict__ s1, const void* __restrict__ s2,
    const void* __restrict__ s3, const void* __restrict__ s4,
    __hip_bfloat16* __restrict__ d0, __hip_bfloat16* __restrict__ d1,
    __hip_bfloat16* __restrict__ d2, __hip_bfloat16* __restrict__ d3,
    __hip_bfloat16* __restrict__ d4, __hip_bfloat16* __restrict__ pe,
    const int* __restrict__ mode) {
  const int tid = threadIdx.x;
  if (blockIdx.z >= 5) {
    // pos-emb: positions K-1..0
    const int p = (blockIdx.z - 5) * 256 + blockIdx.y * 16 + blockIdx.x;
    const float pos = (float)(KL_ - 1 - p);
#pragma unroll
    for (int i = 0; i < 4; i++) {
      int c = tid * 4 + i;
      int f = (c < 512) ? c : c - 512;
      float invf = fexp2(-(float)f * (13.287712379549449f / 512.0f));
      float a = pos * invf;
      float v = (c < 512) ? __sinf(a) : __cosf(a);
      pe[(size_t)p * HID_ + c] = __float2bfloat16(v);
    }
    return;
  }
  const int md = *mode;
  const void* src; __hip_bfloat16* dst;
  switch (blockIdx.z) {
    case 0: src = s0; dst = d0; break;
    case 1: src = s1; dst = d1; break;
    case 2: src = s2; dst = d2; break;
    case 3: src = s3; dst = d3; break;
    default: src = s4; dst = d4; break;
  }
  const int r0 = blockIdx.x * 64, c0 = blockIdx.y * 64;
  __shared__ __hip_bfloat16 t[64][65];
  const int col = tid & 63, r4 = tid >> 6;
#pragma unroll
  for (int i = 0; i < 16; i++)
    t[r4 + i * 4][col] = __float2bfloat16(ldin(src, (size_t)(r0 + r4 + i * 4) * HID_ + c0 + col, md));
  __syncthreads();
#pragma unroll
  for (int i = 0; i < 16; i++)
    dst[(size_t)(c0 + r4 + i * 4) * HID_ + r0 + col] = t[col][r4 + i * 4];
}

// ---------------- fused LayerNorm: rows [0,B*KL) = concat(mem,query); rows >= B*KL = query ----------------
__global__ __launch_bounds__(256) void ln_kernel(
    const void* __restrict__ mem, const void* __restrict__ qry,
    const void* __restrict__ gmem, const void* __restrict__ bmem,
    const void* __restrict__ gq, const void* __restrict__ bq,
    __hip_bfloat16* __restrict__ kvout, __hip_bfloat16* __restrict__ qout,
    const int* __restrict__ mode) {
  const int md = *mode;
  const int row = blockIdx.x;  // 0..B*KL + B*Q - 1
  const void* src;
  const void* gamma; const void* beta;
  size_t base;
  __hip_bfloat16* dst;
  if (row < B_ * KL_) {
    const int b = row / KL_, j = row % KL_;
    if (j < M_) { src = mem; base = ((size_t)b * M_ + j) * HID_; }
    else        { src = qry; base = ((size_t)b * Q_ + (j - M_)) * HID_; }
    gamma = gmem; beta = bmem;
    dst = kvout + (size_t)row * HID_;
  } else {
    const int r = row - B_ * KL_;
    src = qry; base = (size_t)r * HID_;
    gamma = gq; beta = bq;
    dst = qout + (size_t)r * HID_;
  }
  const int tid = threadIdx.x;
  float x[4];
  float s = 0.f, ss = 0.f;
#pragma unroll
  for (int i = 0; i < 4; i++) {
    x[i] = ldin(src, base + i * 256 + tid, md);
    s += x[i]; ss += x[i] * x[i];
  }
#pragma unroll
  for (int o = 32; o > 0; o >>= 1) { s += __shfl_down(s, o); ss += __shfl_down(ss, o); }
  __shared__ float red[8];
  if ((tid & 63) == 0) { red[(tid >> 6) * 2] = s; red[(tid >> 6) * 2 + 1] = ss; }
  __syncthreads();
  float ts = 0.f, tss = 0.f;
#pragma unroll
  for (int i = 0; i < 4; i++) { ts += red[i * 2]; tss += red[i * 2 + 1]; }
  const float mu = ts * (1.f / 1024.f);
  const float var = tss * (1.f / 1024.f) - mu * mu;
  const float rs = rsqrtf(var + 1e-3f);
#pragma unroll
  for (int i = 0; i < 4; i++) {
    int c = i * 256 + tid;
    dst[c] = __float2bfloat16((x[i] - mu) * rs * ldin(gamma, c, md) + ldin(beta, c, md));
  }
}

// ---------------- shared 128x128 BK=64 MFMA core (K=1024) ----------------
__device__ __forceinline__ void mm_core(const __hip_bfloat16* __restrict__ A,
                                        const __hip_bfloat16* __restrict__ BT,
                                        int m0, int n0, int tid,
                                        __hip_bfloat16* sA, __hip_bfloat16* sB,
                                        f32x4 acc[4][4]) {
  const int lane = tid & 63;
  const int w = tid >> 6;
  const int quad = lane >> 4, l16 = lane & 15;
  const int wm = (w >> 1) * 64, wn = (w & 1) * 64;
  for (int kk = 0; kk < HID_ / 64; kk++) {
    const int k0 = kk * 64;
    __syncthreads();
#pragma unroll
    for (int t = 0; t < 4; t++) {
      int c = (w * 4 + t) * 64 + lane;
      int row = c >> 3;
      int cid = (c & 7) ^ (row & 7);
      async_copy16(A + (size_t)(m0 + row) * HID_ + k0 + cid * 8, (char*)sA + c * 16);
      async_copy16(BT + (size_t)(n0 + row) * HID_ + k0 + cid * 8, (char*)sB + c * 16);
    }
    __syncthreads();
#pragma unroll
    for (int half = 0; half < 2; half++) {
      short8 af[4], bf[4];
#pragma unroll
      for (int mt = 0; mt < 4; mt++) {
        int r = wm + mt * 16 + l16;
        af[mt] = *(const short8*)((const char*)sA + r * 128 + (((half * 4 + quad) ^ (r & 7)) * 16));
      }
#pragma unroll
      for (int nt = 0; nt < 4; nt++) {
        int r = wn + nt * 16 + l16;
        bf[nt] = *(const short8*)((const char*)sB + r * 128 + (((half * 4 + quad) ^ (r & 7)) * 16));
      }
#pragma unroll
      for (int mt = 0; mt < 4; mt++)
#pragma unroll
        for (int nt = 0; nt < 4; nt++)
          acc[mt][nt] = __builtin_amdgcn_mfma_f32_16x16x32_bf16(af[mt], bf[nt], acc[mt][nt], 0, 0, 0);
    }
  }
}

// ---------------- gemm_out: aout @ woT -> final output (dtype-switched write) ----------------
__global__ __launch_bounds__(256) void gemm_out(const __hip_bfloat16* __restrict__ A,
                                                const __hip_bfloat16* __restrict__ BT,
                                                void* __restrict__ C,
                                                const int* __restrict__ mode) {
  __shared__ __attribute__((aligned(16))) __hip_bfloat16 sA[128 * 64];
  __shared__ __attribute__((aligned(16))) __hip_bfloat16 sB[128 * 64];
  const int md = *mode;
  const int tid = threadIdx.x;
  const int lane = tid & 63;
  const int w = tid >> 6;
  const int quad = lane >> 4, l16 = lane & 15;
  const int m0 = blockIdx.x * 128;
  const int n0 = blockIdx.y * 128;
  const int wm = (w >> 1) * 64, wn = (w & 1) * 64;
  const f32x4 fz = {0.f, 0.f, 0.f, 0.f};
  f32x4 acc[4][4];
#pragma unroll
  for (int i = 0; i < 4; i++)
#pragma unroll
    for (int j = 0; j < 4; j++) acc[i][j] = fz;
  mm_core(A, BT, m0, n0, tid, sA, sB, acc);
#pragma unroll
  for (int mt = 0; mt < 4; mt++)
#pragma unroll
    for (int nt = 0; nt < 4; nt++)
#pragma unroll
      for (int rg = 0; rg < 4; rg++) {
        int r = m0 + wm + mt * 16 + quad * 4 + rg;
        int cc = n0 + wn + nt * 16 + l16;
        size_t idx = (size_t)r * HID_ + cc;
        if (md) ((float*)C)[idx] = acc[mt][nt][rg];
        else ((__hip_bfloat16*)C)[idx] = __float2bfloat16(acc[mt][nt][rg]);
      }
}

// ---------------- merged mid-pipeline GEMMs: dualv (0..1023) + q (1024..1279) + bt128 (1280..1535) ----
// One launch -> 4 blocks/CU co-resident (34.8 KB unioned LDS) instead of three serial
// launches at 1 block/CU each. Same 128x128 BK=64 core; per-path epilogues.
__global__ __launch_bounds__(256) void gemm_mid(
    const __hip_bfloat16* __restrict__ kvln, const __hip_bfloat16* __restrict__ wkT,
    __hip_bfloat16* __restrict__ kpb, __hip_bfloat16* __restrict__ vpt,
    const __hip_bfloat16* __restrict__ qln, const __hip_bfloat16* __restrict__ wqT,
    const void* __restrict__ rwb, const void* __restrict__ rrb,
    __hip_bfloat16* __restrict__ qpw, __hip_bfloat16* __restrict__ qpr,
    const __hip_bfloat16* __restrict__ pe, const __hip_bfloat16* __restrict__ wrT,
    __hip_bfloat16* __restrict__ relp,
    const int* __restrict__ mode) {
  __shared__ __attribute__((aligned(16))) char smem[128 * 136 * 2];  // 34816 B >= sA+sB (32768)
  __hip_bfloat16* sA = (__hip_bfloat16*)smem;
  __hip_bfloat16* sB = (__hip_bfloat16*)(smem + 16384);
  short* sT = (short*)smem;

  const int bid = blockIdx.x;
  int path, m0, n0;
  const __hip_bfloat16* A;
  const __hip_bfloat16* BT;
  if (bid < 1024) {
    path = 0; m0 = (bid & 63) * 128; n0 = (bid >> 6) * 128;
    A = kvln; BT = wkT;                 // wkT contiguous with wvT (n0 spans 0..1920)
  } else if (bid < 1280) {
    path = 1; int t = bid - 1024; m0 = (t & 31) * 128; n0 = (t >> 5) * 128;
    A = qln; BT = wqT;
  } else {
    path = 2; int t = bid - 1280; m0 = (t & 31) * 128; n0 = (t >> 5) * 128;
    A = pe; BT = wrT;
  }

  const int tid = threadIdx.x;
  const int lane = tid & 63;
  const int w = tid >> 6;
  const int quad = lane >> 4, l16 = lane & 15;
  const int wm = (w >> 1) * 64, wn = (w & 1) * 64;
  const f32x4 fz = {0.f, 0.f, 0.f, 0.f};
  f32x4 acc[4][4];
#pragma unroll
  for (int i = 0; i < 4; i++)
#pragma unroll
    for (int j = 0; j < 4; j++) acc[i][j] = fz;

  mm_core(A, BT, m0, n0, tid, sA, sB, acc);

  if (path == 1) {
    // ---- q-projection dual-bias epilogue ----
    const int md = *mode;
    float bw[4], br[4];
#pragma unroll
    for (int nt = 0; nt < 4; nt++) {
      int cc = n0 + wn + nt * 16 + l16;
      bw[nt] = ldin(rwb, cc, md);
      br[nt] = ldin(rrb, cc, md);
    }
#pragma unroll
    for (int mt = 0; mt < 4; mt++)
#pragma unroll
      for (int nt = 0; nt < 4; nt++)
#pragma unroll
        for (int rg = 0; rg < 4; rg++) {
          int r = m0 + wm + mt * 16 + quad * 4 + rg;
          int cc = n0 + wn + nt * 16 + l16;
          size_t idx = (size_t)r * HID_ + cc;
          float a = acc[mt][nt][rg];
          qpw[idx] = __float2bfloat16((a + bw[nt]) * LSCL);
          qpr[idx] = __float2bfloat16((a + br[nt]) * LSCL);
        }
  } else if (path == 2) {
    // ---- rel-position GEMM: plain bf16 write ----
#pragma unroll
    for (int mt = 0; mt < 4; mt++)
#pragma unroll
      for (int nt = 0; nt < 4; nt++)
#pragma unroll
        for (int rg = 0; rg < 4; rg++) {
          int r = m0 + wm + mt * 16 + quad * 4 + rg;
          int cc = n0 + wn + nt * 16 + l16;
          relp[(size_t)r * HID_ + cc] = __float2bfloat16(acc[mt][nt][rg]);
        }
  } else if (n0 < HID_) {
    // ---- dualv K half: row-major write ----
#pragma unroll
    for (int mt = 0; mt < 4; mt++)
#pragma unroll
      for (int nt = 0; nt < 4; nt++)
#pragma unroll
        for (int rg = 0; rg < 4; rg++) {
          int r = m0 + wm + mt * 16 + quad * 4 + rg;
          int cc = n0 + wn + nt * 16 + l16;
          kpb[(size_t)r * HID_ + cc] = __float2bfloat16(acc[mt][nt][rg]);
        }
  } else {
    // ---- dualv V half: transpose through sT (unioned with sA/sB) -> vpt ----
    __syncthreads();  // all MFMA LDS reads done before sT overwrites sA/sB space
#pragma unroll
    for (int mt = 0; mt < 4; mt++)
#pragma unroll
      for (int nt = 0; nt < 4; nt++) {
        int r = wm + mt * 16 + quad * 4;   // local j base (rg 0..3 consecutive)
        int cc = wn + nt * 16 + l16;       // local col
        short4v pk;
#pragma unroll
        for (int rg = 0; rg < 4; rg++) pk[rg] = bfbits(acc[mt][nt][rg]);
        *(short4v*)&sT[cc * 136 + r] = pk;
      }
    __syncthreads();
    const int b = m0 >> 12;            // 4096 rows per batch
    const int j0g = m0 & (KL_ - 1);
    const int cg0 = n0 - HID_;
#pragma unroll
    for (int it = 0; it < 16; it++) {
      int cc = it * 8 + w * 2 + (lane >> 5);
      int jj = (lane & 31) * 4;
      int cg = cg0 + cc;
      int h = cg >> 6, d = cg & 63;
      short4v v = *(const short4v*)&sT[cc * 136 + jj];
      *(short4v*)(vpt + (((size_t)(b * H_ + h)) * D_ + d) * KL_ + j0g + jj) = v;
    }
  }
}

// ---------------- fused relative attention, 32x32 MFMA, SPLIT-K halves ----------------
// grid 1024 = 32 bh x 16 rk x 2 halves, longest-first (rk descending). Each half runs
// (17+rk) tiles of the inner loop and writes UNNORMALIZED partials:
// opart[half] (f32 O-accum) + mlbuf[half] (m, l, df per q-row). merge_kernel combines.
__global__ __launch_bounds__(256, 2) void attn_kernel(
    const __hip_bfloat16* __restrict__ qpw, const __hip_bfloat16* __restrict__ qpr,
    const __hip_bfloat16* __restrict__ kp, const __hip_bfloat16* __restrict__ vpt,
    const __hip_bfloat16* __restrict__ relp,
    const void* __restrict__ spanv,
    float* __restrict__ opart, float* __restrict__ mlbuf,
    const int* __restrict__ mode) {
  const int md = *mode;
  const int bid = blockIdx.x;          // 0..1023
  const int g = bid >> 1, half = bid & 1;
  const int rk = 15 - (g >> 5);        // longest (rk=15) dispatched first
  const int bh = g & 31;
  const int i0 = rk << 7;
  const int b = bh >> 4, h = bh & 15;
  const int nt = 34 + 2 * rk;          // total tiles for this (i0); always even
  const int nt2 = nt >> 1;
  const int kt0 = half ? nt2 : 0;
  const int kt1 = half ? nt : nt2;

  const int tid = threadIdx.x;
  const int lane = tid & 63;
  const int w = tid >> 6;
  const int l31 = lane & 31, hi = lane >> 5;
  const int di = w * 32 + l31;          // this thread's softmax row (block-local)
  const int iRow = i0 + di;

  __shared__ __attribute__((aligned(16))) __hip_bfloat16 sk[64 * 64];     // 8 KB K tile
  __shared__ __attribute__((aligned(16))) __hip_bfloat16 srel[192 * 64];  // 24 KB circular rel band
  __shared__ __attribute__((aligned(16))) __hip_bfloat16 svt[64 * 64];    // 8 KB V^T tile
  __shared__ __attribute__((aligned(16))) short sTP[128 * 100];           // 25 KB T rows, stride 200 B

  const int rb = di * 200;              // private row base (bytes), 8B-aligned
  const int sw = l31 & 7;               // swizzle key (== row&7 for all operand reads)

  const __hip_bfloat16* kbase = kp + (size_t)b * KL_ * HID_ + h * D_;
  const __hip_bfloat16* vtb = vpt + ((size_t)(b * H_ + h)) * D_ * KL_;
  const float sv = ldin(spanv, h, md);
  const float svQ = sv * (float)Q_;
  const int pb0 = Q_ - RT_ - i0;
  const int wof = (3 - w) * 32;         // this wave's T-band p-window offset
  const int jb0 = kt0 * WT_;            // this half's starting column

  const f32x16 z16 = {0.f,0.f,0.f,0.f,0.f,0.f,0.f,0.f,0.f,0.f,0.f,0.f,0.f,0.f,0.f,0.f};

  // ---- q' / q'' fragments: direct global loads of own row (one-time) ----
  short8 qf[4], qrf[4];
  {
    const size_t qofs = ((size_t)(b * Q_ + iRow)) * HID_ + h * D_;
#pragma unroll
    for (int ks = 0; ks < 4; ks++) {
      qf[ks]  = *(const short8*)(qpw + qofs + ks * 16 + hi * 8);
      qrf[ks] = *(const short8*)(qpr + qofs + ks * 16 + hi * 8);
    }
  }

  // ---- first tile staged via DMA (K, full 192-row rel band, V^T) at column jb0 ----
  {
#pragma unroll
    for (int t = 0; t < 2; t++) {
      int c = (w * 2 + t) * 64 + lane;
      int row = c >> 3;
      int cid = (c & 7) ^ (row & 7);
      async_copy16(kbase + (size_t)(jb0 + row) * HID_ + cid * 8, (char*)sk + c * 16);
      async_copy16(vtb + (size_t)row * KL_ + jb0 + cid * 8, (char*)svt + c * 16);
    }
#pragma unroll
    for (int t = 0; t < 6; t++) {
      int c = (w * 6 + t) * 64 + lane;
      int row = c >> 3;                  // 0..191
      int cid = (c & 7) ^ (row & 7);
      int p = pb0 + jb0 + row; p = p < KL_ ? p : KL_ - 1;
      async_copy16(relp + (size_t)p * HID_ + h * D_ + cid * 8, (char*)srel + c * 16);
    }
  }

  float mrow = -3e38f, lrow = 0.f, dfrow = 0.f;
  f32x16 oacc[2];
  oacc[0] = z16; oacc[1] = z16;
  int rot = 0;                          // local circular rotation, (iter % 3) * 64

  for (int kt = kt0; kt < kt1; kt++) {
    const int j0 = kt * WT_;

    __syncthreads();  // B: tile kt staging (DMA or ds_writes) visible

    // ---- prefetch tile kt+1 into registers (issued before compute; committed after) ----
    short8 rK[2], rR[2], rV[2];
    const bool pf = (kt + 1 < kt1);
    {
      int j0n = j0 + WT_; if (j0n > KL_ - WT_) j0n = KL_ - WT_;
#pragma unroll
      for (int t = 0; t < 2; t++) {
        int c = (w * 2 + t) * 64 + lane;
        int row = c >> 3;
        int cid = (c & 7) ^ (row & 7);
        rK[t] = *(const short8*)(kbase + (size_t)(j0n + row) * HID_ + cid * 8);
        rV[t] = *(const short8*)(vtb + (size_t)row * KL_ + j0n + cid * 8);
        int p = pb0 + (kt + 1) * 64 + 128 + row; p = p < KL_ ? p : KL_ - 1;
        rR[t] = *(const short8*)(relp + (size_t)p * HID_ + h * D_ + cid * 8);
      }
    }
    __builtin_amdgcn_sched_barrier(0);  // pin load issue above the compute phase

    // ---- S^T[j][i] = K . q'^T ----
    __builtin_amdgcn_s_setprio(1);
    f32x16 S[2];
    S[0] = z16; S[1] = z16;
#pragma unroll
    for (int mt = 0; mt < 2; mt++) {
      const char* rowp = (const char*)sk + (mt * 32 + l31) * 128;
#pragma unroll
      for (int ks = 0; ks < 4; ks++) {
        short8 af = *(const short8*)(rowp + (((ks * 2 + hi) ^ sw) * 16));
        S[mt] = __builtin_amdgcn_mfma_f32_32x32x16_bf16(af, qf[ks], S[mt], 0, 0, 0);
      }
    }

    // ---- T band (wave's 96-row p-window) = rel . q''^T, store into own sTP row ----
#pragma unroll
    for (int mt = 0; mt < 3; mt++) {
      f32x16 T = z16;
      int rr = wof + mt * 32 + l31 + rot; if (rr >= 192) rr -= 192;
      const char* rowp = (const char*)srel + rr * 128;
#pragma unroll
      for (int ks = 0; ks < 4; ks++) {
        short8 af = *(const short8*)(rowp + (((ks * 2 + hi) ^ sw) * 16));
        T = __builtin_amdgcn_mfma_f32_32x32x16_bf16(af, qrf[ks], T, 0, 0, 0);
      }
#pragma unroll
      for (int r2 = 0; r2 < 4; r2++) {
        short4v pk;
#pragma unroll
        for (int r4 = 0; r4 < 4; r4++) pk[r4] = bfbits(T[r2 * 4 + r4]);
        *(short4v*)((char*)sTP + rb + (mt * 32 + 8 * r2 + 4 * hi) * 2) = pk;
      }
    }
    __builtin_amdgcn_s_setprio(0);

    // ---- gather with per-row shift (own row, in-order DS) ----
    {
      const char* tb2 = (const char*)sTP + rb + (31 - l31 + 4 * hi) * 2;
#pragma unroll
      for (int mt = 0; mt < 2; mt++)
#pragma unroll
        for (int r2 = 0; r2 < 4; r2++)
#pragma unroll
          for (int r4 = 0; r4 < 4; r4++)
            S[mt][r2 * 4 + r4] +=
                __bfloat162float(*(const __hip_bfloat16*)(tb2 + (mt * 32 + 8 * r2 + r4) * 2));
    }

    // ---- logits (log2 units), causal mask only on tiles that can need it ----
    const bool causalT = (j0 + WT_ - 1 - i0) > M_;
    if (causalT) {
#pragma unroll
      for (int mt = 0; mt < 2; mt++)
#pragma unroll
        for (int r2 = 0; r2 < 4; r2++)
#pragma unroll
          for (int r4 = 0; r4 < 4; r4++) {
            int j = j0 + mt * 32 + 8 * r2 + 4 * hi + r4;
            if (j - iRow > M_) S[mt][r2 * 4 + r4] = -1e30f;
          }
    }
    // tree max: depth ~6 instead of 32-deep serial chain (clang fuses to v_max3)
    float m8[8];
#pragma unroll
    for (int g2 = 0; g2 < 8; g2++) {
      int mt = g2 >> 2, r2 = g2 & 3;
      m8[g2] = fmaxf(fmaxf(S[mt][r2 * 4 + 0], S[mt][r2 * 4 + 1]),
                     fmaxf(S[mt][r2 * 4 + 2], S[mt][r2 * 4 + 3]));
    }
    float mnew = fmaxf(mrow,
        fmaxf(fmaxf(fmaxf(m8[0], m8[1]), fmaxf(m8[2], m8[3])),
              fmaxf(fmaxf(m8[4], m8[5]), fmaxf(m8[6], m8[7]))));
    mnew = fmaxf(mnew, __shfl_xor(mnew, 32));
    // T13 defer-max: skip rescale while tile max growth <= 8 (P bounded by 2^8)
    if (!__all(mnew - mrow <= 8.f)) {
      const float alpha = fexp2(mrow - mnew);
      mrow = mnew;
      lrow *= alpha; dfrow *= alpha;
#pragma unroll
      for (int dt = 0; dt < 2; dt++)
#pragma unroll
        for (int rg = 0; rg < 16; rg++) oacc[dt][rg] *= alpha;
    }

    // ---- P = exp2(S-m) in-register; span deficit on ramp tiles; permlane assembly ----
    const bool maskT = (j0 + WT_ > M_) && ((float)j0 < (float)M_ + 33.f - svQ);
    short8 paf[4];
#pragma unroll
    for (int mt = 0; mt < 2; mt++) {
      unsigned Pp[4][2];
#pragma unroll
      for (int r2 = 0; r2 < 4; r2++) {
        short4v g3;
        float pvv[4];
#pragma unroll
        for (int r4 = 0; r4 < 4; r4++) {
          float pv = fexp2(S[mt][r2 * 4 + r4] - mrow);
          pvv[r4] = pv;
          float pm = pv;
          if (maskT) {
            int j = j0 + mt * 32 + 8 * r2 + 4 * hi + r4;
            if (j >= M_) {
              float t0 = (float)(j - M_) + svQ;
              float mk = fminf(fmaxf(t0 * (1.0f / 33.0f), 0.f), 1.f);
              pm = pv * mk;
              dfrow += pv - pm;
            }
          }
          g3[r4] = bfbits(pm);
        }
        lrow += (pvv[0] + pvv[1]) + (pvv[2] + pvv[3]);  // tree partial, short dep chain
        union { short4v s; unsigned u[2]; } cv; cv.s = g3;
        Pp[r2][0] = cv.u[0]; Pp[r2][1] = cv.u[1];
      }
#pragma unroll
      for (int hf = 0; hf < 2; hf++) {
        uint2v rA = __builtin_amdgcn_permlane32_swap(Pp[hf * 2][0], Pp[hf * 2 + 1][0], false, false);
        uint2v rB = __builtin_amdgcn_permlane32_swap(Pp[hf * 2][1], Pp[hf * 2 + 1][1], false, false);
        union { unsigned u[4]; short8 s; } asm8;
        asm8.u[0] = rA[0]; asm8.u[1] = rB[0]; asm8.u[2] = rA[1]; asm8.u[3] = rB[1];
        paf[mt * 2 + hf] = asm8.s;
      }
    }

    // ---- PV (swapped): A = V^T rows (M=d), B = P (N = own q-row) ----
    __builtin_amdgcn_s_setprio(1);
#pragma unroll
    for (int dt = 0; dt < 2; dt++) {
      const char* rowp = (const char*)svt + (dt * 32 + l31) * 128;
#pragma unroll
      for (int ks = 0; ks < 4; ks++) {
        short8 bfv = *(const short8*)(rowp + (((ks * 2 + hi) ^ sw) * 16));
        oacc[dt] = __builtin_amdgcn_mfma_f32_32x32x16_bf16(bfv, paf[ks], oacc[dt], 0, 0, 0);
      }
    }
    __builtin_amdgcn_s_setprio(0);

    __syncthreads();  // A: all LDS consumers of tile kt done

    // ---- commit prefetched tile kt+1 to LDS (vmcnt drain here, after compute) ----
    if (pf) {
#pragma unroll
      for (int t = 0; t < 2; t++) {
        int c = (w * 2 + t) * 64 + lane;
        int row = c >> 3;
        *(short8*)((char*)sk + c * 16) = rK[t];
        *(short8*)((char*)svt + c * 16) = rV[t];
        *(short8*)((char*)srel + (rot + row) * 128 + (c & 7) * 16) = rR[t];
      }
    }
    rot += 64; if (rot == 192) rot = 0;
  }

  // ---- epilogue: write unnormalized partials (f32 O + per-row m/l/df) ----
  lrow += __shfl_xor(lrow, 32);
  dfrow += __shfl_xor(dfrow, 32);
  float* ob = opart + (size_t)half * B_ * Q_ * HID_ + ((size_t)(b * Q_ + iRow)) * HID_ + h * D_;
#pragma unroll
  for (int dt = 0; dt < 2; dt++)
#pragma unroll
    for (int r2 = 0; r2 < 4; r2++) {
      f32x4 o = {oacc[dt][r2 * 4 + 0], oacc[dt][r2 * 4 + 1],
                 oacc[dt][r2 * 4 + 2], oacc[dt][r2 * 4 + 3]};
      *(f32x4*)(ob + dt * 32 + 8 * r2 + 4 * hi) = o;
    }
  if (hi == 0) {
    f32x4 mlv = {mrow, lrow, dfrow, 0.f};
    *(f32x4*)(mlbuf + ((size_t)half * B_ * H_ * Q_ + ((size_t)(b * H_ + h)) * Q_ + iRow) * 4) = mlv;
  }
}

// ---------------- split-K merge: aout = (o0*a0 + o1*a1) / denom ----------------
__global__ __launch_bounds__(256) void merge_kernel(
    const float* __restrict__ opart, const float* __restrict__ mlbuf,
    __hip_bfloat16* __restrict__ aout) {
  const int bq = blockIdx.x;              // 0..B*Q-1
  const int b = bq >> 11, q = bq & 2047;
  const int t = threadIdx.x;
  const int h = t >> 4, dg = (t & 15) * 4;
  const size_t mlidx = (((size_t)(b * H_ + h)) * Q_ + q) * 4;
  const size_t MLH = (size_t)B_ * H_ * Q_ * 4;
  f32x4 ml0 = *(const f32x4*)(mlbuf + mlidx);
  f32x4 ml1 = *(const f32x4*)(mlbuf + MLH + mlidx);
  const float ms = fmaxf(ml0[0], ml1[0]);
  const float a0 = fexp2(ml0[0] - ms), a1 = fexp2(ml1[0] - ms);
  const float l = ml0[1] * a0 + ml1[1] * a1;
  const float df = ml0[2] * a0 + ml1[2] * a1;
  const float r = 1.f / ((l - df) + 1e-8f * l);
  const size_t oidx = (size_t)bq * HID_ + h * D_ + dg;
  const size_t OH = (size_t)B_ * Q_ * HID_;
  f32x4 o0 = *(const f32x4*)(opart + oidx);
  f32x4 o1 = *(const f32x4*)(opart + OH + oidx);
  short4v o;
#pragma unroll
  for (int r4 = 0; r4 < 4; r4++) o[r4] = bfbits((o0[r4] * a0 + o1[r4] * a1) * r);
  *(short4v*)(aout + oidx) = o;
}

// ---------------- launcher ----------------
extern "C" void kernel_launch(void* const* d_in, const int* in_sizes, int n_in,
                              void* d_out, int out_size, void* d_ws, size_t ws_size,
                              hipStream_t stream) {
  const void* query  = d_in[0];
  const void* memory = d_in[1];
  const void* Wq = d_in[2];
  const void* Wk = d_in[3];
  const void* Wv = d_in[4];
  const void* Wo = d_in[5];
  const void* Wr = d_in[6];
  const void* gmem = d_in[7];
  const void* bmem = d_in[8];
  const void* gq = d_in[9];
  const void* bq = d_in[10];
  const void* rwb = d_in[11];
  const void* rrb = d_in[12];
  const void* spanv = d_in[13];

  char* ws = (char*)d_ws;
  size_t off = 0;
  auto alloc = [&](size_t bytes) -> char* {
    char* p = ws + off;
    off += (bytes + 255) & ~(size_t)255;
    return p;
  };
  int* flag = (int*)alloc(256);
  const size_t SZ_W = (size_t)HID_ * HID_ * 2;
  __hip_bfloat16* wqT = (__hip_bfloat16*)alloc(SZ_W);
  __hip_bfloat16* wkT = (__hip_bfloat16*)alloc(SZ_W);   // contiguous with wvT (SZ_W is 256B-aligned)
  __hip_bfloat16* wvT = (__hip_bfloat16*)alloc(SZ_W);
  __hip_bfloat16* wrT = (__hip_bfloat16*)alloc(SZ_W);
  __hip_bfloat16* woT = (__hip_bfloat16*)alloc(SZ_W);
  // kvln + qln + pe are dead after the projection GEMMs; their contiguous 33.55 MB
  // is reused as the f32 split-K partial buffer (exactly 2 * B*Q*HID * 4 bytes).
  __hip_bfloat16* kvln = (__hip_bfloat16*)alloc((size_t)B_ * KL_ * HID_ * 2);
  __hip_bfloat16* qln  = (__hip_bfloat16*)alloc((size_t)B_ * Q_ * HID_ * 2);
  __hip_bfloat16* pe   = (__hip_bfloat16*)alloc((size_t)KL_ * HID_ * 2);
  __hip_bfloat16* qpw  = (__hip_bfloat16*)alloc((size_t)B_ * Q_ * HID_ * 2);
  __hip_bfloat16* qpr  = (__hip_bfloat16*)alloc((size_t)B_ * Q_ * HID_ * 2);
  __hip_bfloat16* kpb  = (__hip_bfloat16*)alloc((size_t)B_ * KL_ * HID_ * 2);
  __hip_bfloat16* vptb = (__hip_bfloat16*)alloc((size_t)B_ * KL_ * HID_ * 2);  // V, transposed per-head
  __hip_bfloat16* relp = (__hip_bfloat16*)alloc((size_t)KL_ * HID_ * 2);
  __hip_bfloat16* aout = (__hip_bfloat16*)alloc((size_t)B_ * Q_ * HID_ * 2);
  float* mlbuf = (float*)alloc((size_t)2 * B_ * H_ * Q_ * 4 * sizeof(float));
  float* opart = (float*)kvln;   // 33.55 MB f32 partials overlay (kvln+qln+pe)

  dim3 tb(256);
  detect_kernel<<<dim3(1), tb, 0, stream>>>((const unsigned int*)query, flag);

  wtpe_kernel<<<dim3(16, 16, 21), tb, 0, stream>>>(Wq, Wk, Wv, Wr, Wo,
                                                   wqT, wkT, wvT, wrT, woT, pe, flag);

  ln_kernel<<<dim3(B_ * KL_ + B_ * Q_), tb, 0, stream>>>(memory, query, gmem, bmem, gq, bq,
                                                         kvln, qln, flag);

  gemm_mid<<<dim3(1536), tb, 0, stream>>>(kvln, wkT, kpb, vptb,
                                          qln, wqT, rwb, rrb, qpw, qpr,
                                          pe, wrT, relp, flag);

  attn_kernel<<<dim3(1024), tb, 0, stream>>>(qpw, qpr, kpb, vptb, relp, spanv,
                                             opart, mlbuf, flag);
  merge_kernel<<<dim3(B_ * Q_), tb, 0, stream>>>(opart, mlbuf, aout);

  gemm_out<<<dim3(B_ * Q_ / 128, HID_ / 128), tb, 0, stream>>>(aout, woT, d_out, flag);

  (void)in_sizes; (void)n_in; (void)out_size; (void)ws_size;
}